// Round 2
// baseline (1110.776 us; speedup 1.0000x reference)
//
#include <hip/hip_runtime.h>

constexpr int NN   = 50000;   // nodes
constexpr int NPAD = 50016;   // padded to multiple of 32 for conv tiles
constexpr int NE   = 600000;  // edges
constexpr int NG   = 512;     // graphs
constexpr int HD   = 128;     // hidden
constexpr float BN_EPS = 1e-5f;
constexpr int CWS  = HD*HD + 2*HD + HD;  // per-layer combined-weight slot (floats): Wc[128x128], wce[2x128], bc[128]

// ---------------- preprocessing ----------------

__global__ __launch_bounds__(256) void k_edge_pre(
    const int* __restrict__ ei, const float* __restrict__ x, const float* __restrict__ ea,
    int* __restrict__ deg, float* __restrict__ Sx, float* __restrict__ Se) {
  int e = blockIdx.x * 256 + threadIdx.x;
  if (e >= NE) return;
  int s = ei[e], d = ei[NE + e];
  atomicAdd(&deg[d], 1);
  float2 eav = *(const float2*)(ea + 2 * e);
  atomicAdd(&Se[2 * d + 0], eav.x);
  atomicAdd(&Se[2 * d + 1], eav.y);
  float4 xv = *(const float4*)(x + 4 * s);
  atomicAdd(&Sx[4 * d + 0], xv.x);
  atomicAdd(&Sx[4 * d + 1], xv.y);
  atomicAdd(&Sx[4 * d + 2], xv.z);
  atomicAdd(&Sx[4 * d + 3], xv.w);
}

__global__ __launch_bounds__(1024) void k_scanA(const int* __restrict__ deg,
                                                int* __restrict__ rowptr, int* __restrict__ bsum) {
  __shared__ int sm[1024];
  int t = threadIdx.x, b = blockIdx.x;
  int i = b * 1024 + t;
  int v = (i < NN) ? deg[i] : 0;
  sm[t] = v;
  __syncthreads();
  for (int off = 1; off < 1024; off <<= 1) {
    int add = (t >= off) ? sm[t - off] : 0;
    __syncthreads();
    sm[t] += add;
    __syncthreads();
  }
  int incl = sm[t];
  if (i < NN) rowptr[i] = incl - v;   // exclusive within chunk
  if (t == 1023) bsum[b] = incl;
}

__global__ void k_scanB(int* bsum, int nb, int* rowptr) {
  if (threadIdx.x == 0 && blockIdx.x == 0) {
    int acc = 0;
    for (int b = 0; b < nb; b++) { int v = bsum[b]; bsum[b] = acc; acc += v; }
    rowptr[NN] = NE;
  }
}

__global__ __launch_bounds__(1024) void k_scanC(int* rowptr, const int* __restrict__ bsum) {
  int i = blockIdx.x * 1024 + threadIdx.x;
  if (i < NN) rowptr[i] += bsum[blockIdx.x];
}

__global__ __launch_bounds__(256) void k_scatter(
    const int* __restrict__ ei, const int* __restrict__ rowptr,
    int* __restrict__ fill, int* __restrict__ csr) {
  int e = blockIdx.x * 256 + threadIdx.x;
  if (e >= NE) return;
  int s = ei[e], d = ei[NE + e];
  int pos = rowptr[d] + atomicAdd(&fill[d], 1);
  csr[pos] = s;
}

// combined weights: Wc = We_h @ Wn, wce = We_e @ Wn, bc = be @ Wn
__global__ __launch_bounds__(128) void k_combine(
    const float* __restrict__ We0, const float* __restrict__ be0, const float* __restrict__ Wn0,
    const float* __restrict__ We_s, const float* __restrict__ be_s, const float* __restrict__ Wn_s,
    float* __restrict__ cw) {
  int l = blockIdx.x / 131;
  int r = blockIdx.x % 131;
  int j = threadIdx.x;
  float* slot = cw + (size_t)l * CWS;
  const float* Wn;
  const float* Arow;
  float* dst;
  if (l == 0) {
    Wn = Wn0;
    if (r < 4)       { Arow = We0 + r * HD; dst = slot + r * HD; }
    else if (r < 6)  { Arow = We0 + r * HD; dst = slot + HD * HD + (r - 4) * HD; }
    else if (r == 6) { Arow = be0;          dst = slot + HD * HD + 2 * HD; }
    else return;
  } else {
    int li = l - 1;
    Wn = Wn_s + (size_t)li * HD * HD;
    const float* We = We_s + (size_t)li * 130 * HD;
    if (r < 128)      { Arow = We + r * HD;  dst = slot + r * HD; }
    else if (r < 130) { Arow = We + r * HD;  dst = slot + HD * HD + (r - 128) * HD; }
    else              { Arow = be_s + li * HD; dst = slot + HD * HD + 2 * HD; }
  }
  float acc = 0.f;
  for (int t = 0; t < HD; t++) acc = fmaf(Arow[t], Wn[t * HD + j], acc);
  dst[j] = acc;
}

// ---------------- layer 0 (K=4) ----------------

__global__ __launch_bounds__(256) void k_layer0(
    const float* __restrict__ x, const float* __restrict__ Sx, const float* __restrict__ Se,
    const int* __restrict__ deg, const float* __restrict__ cw0,
    const float* __restrict__ bno0, const float* __restrict__ g0, const float* __restrict__ bt0,
    const float* __restrict__ m0, const float* __restrict__ v0,
    const float* __restrict__ Wr0, const float* __restrict__ br0,
    float* __restrict__ outp) {
  int tid = threadIdx.x;
  int row = blockIdx.x * 2 + (tid >> 7);
  int c = tid & 127;
  const float* Wc0  = cw0;                 // [4][128]
  const float* wce0 = cw0 + HD * HD;       // [2][128]
  const float* bc0  = cw0 + HD * HD + 2 * HD;
  float y = 0.f;
#pragma unroll
  for (int k = 0; k < 4; k++) y = fmaf(Sx[row * 4 + k], Wc0[k * HD + c], y);
  y = fmaf(Se[row * 2 + 0], wce0[c], y);
  y = fmaf(Se[row * 2 + 1], wce0[HD + c], y);
  float dg = (float)deg[row];
  y = fmaf(dg, bc0[c], y);
  float dgi = 1.0f / fmaxf(dg, 1.0f);
  y = y * dgi + bno0[c];
  float sc = g0[c] * rsqrtf(v0[c] + BN_EPS);
  float sh = bt0[c] - m0[c] * sc;
  y = y * sc + sh;
  float r = br0[c];
#pragma unroll
  for (int k = 0; k < 4; k++) r = fmaf(x[row * 4 + k], Wr0[k * HD + c], r);
  outp[(size_t)row * HD + c] = fmaxf(y + r, 0.f);
}

// ---------------- aggregation: S[i] = sum_{e->i} h[src_e] ----------------
// 256-thread blocks, one 64-lane wave per node (4 nodes/block).

__global__ __launch_bounds__(256) void k_aggregate(
    const float* __restrict__ h, const int* __restrict__ rowptr, const int* __restrict__ csr,
    float* __restrict__ S) {
  int i = blockIdx.x * 4 + (threadIdx.x >> 6);
  if (i >= NN) return;
  int lane = threadIdx.x & 63;
  int e0 = rowptr[i], e1 = rowptr[i + 1];
  float2 acc = make_float2(0.f, 0.f);
  for (int e = e0; e < e1; ++e) {
    int s = csr[e];
    float2 v = *(const float2*)(h + (size_t)s * HD + 2 * lane);
    acc.x += v.x;
    acc.y += v.y;
  }
  *(float2*)(S + (size_t)i * HD + 2 * lane) = acc;
}

// ---------------- conv GEMM + fused epilogue (in-place on S) ----------------
// LDS: 32KB weight chunk (64 rows) + 16KB S tile = 48KB -> 3 blocks/CU.

__global__ __launch_bounds__(256) void k_conv(
    const float* __restrict__ S, const float* __restrict__ hres, float* __restrict__ outp,
    const float* __restrict__ cwl,
    const float* __restrict__ bno, const float* __restrict__ gam, const float* __restrict__ bet,
    const float* __restrict__ mu, const float* __restrict__ var,
    const float* __restrict__ Se, const int* __restrict__ deg) {
  __shared__ float Ws[64 * HD];    // 32 KB: half of combined weight (64 K-rows)
  __shared__ float St[32 * HD];    // 16 KB: S tile (32 rows)
  int tid = threadIdx.x;
  size_t rowbase = (size_t)blockIdx.x * 32;
  {
    const float4* s4 = (const float4*)(S + rowbase * HD);
    float4* st4 = (float4*)St;
#pragma unroll
    for (int i = 0; i < 4; i++) st4[tid + 256 * i] = s4[tid + 256 * i];
  }
  int cg = tid & 31;   // cols cg*4 .. +3
  int rg = tid >> 5;   // rows rg*4 .. +3
  float acc[4][4];
#pragma unroll
  for (int r = 0; r < 4; r++)
#pragma unroll
    for (int c = 0; c < 4; c++) acc[r][c] = 0.f;
  const float4* Ws4 = (const float4*)Ws;
#pragma unroll
  for (int kc = 0; kc < 2; kc++) {
    // stage 64 K-rows of the weight (64*128 floats = 2048 float4)
    {
      const float4* src = (const float4*)(cwl + kc * 64 * HD);
      float4* dst = (float4*)Ws;
#pragma unroll
      for (int i = 0; i < 8; i++) dst[tid + 256 * i] = src[tid + 256 * i];
    }
    __syncthreads();
    for (int k = 0; k < 64; k++) {
      float4 w = Ws4[k * 32 + cg];
#pragma unroll
      for (int r = 0; r < 4; r++) {
        float s = St[(rg * 4 + r) * HD + kc * 64 + k];
        acc[r][0] = fmaf(s, w.x, acc[r][0]);
        acc[r][1] = fmaf(s, w.y, acc[r][1]);
        acc[r][2] = fmaf(s, w.z, acc[r][2]);
        acc[r][3] = fmaf(s, w.w, acc[r][3]);
      }
    }
    __syncthreads();
  }
  int c0 = cg * 4;
  const float* wce = cwl + HD * HD;
  const float* bcp = cwl + HD * HD + 2 * HD;
  float4 w0   = *(const float4*)(wce + c0);
  float4 w1   = *(const float4*)(wce + HD + c0);
  float4 bcv  = *(const float4*)(bcp + c0);
  float4 bnov = *(const float4*)(bno + c0);
  float4 gv   = *(const float4*)(gam + c0);
  float4 btv  = *(const float4*)(bet + c0);
  float4 mv   = *(const float4*)(mu + c0);
  float4 vv   = *(const float4*)(var + c0);
  float sc0 = gv.x * rsqrtf(vv.x + BN_EPS), sh0 = btv.x - mv.x * sc0;
  float sc1 = gv.y * rsqrtf(vv.y + BN_EPS), sh1 = btv.y - mv.y * sc1;
  float sc2 = gv.z * rsqrtf(vv.z + BN_EPS), sh2 = btv.z - mv.z * sc2;
  float sc3 = gv.w * rsqrtf(vv.w + BN_EPS), sh3 = btv.w - mv.w * sc3;
#pragma unroll
  for (int r = 0; r < 4; r++) {
    size_t row = rowbase + rg * 4 + r;
    float2 sev = *(const float2*)(Se + row * 2);
    float dg = (float)deg[row];
    float dgi = 1.0f / fmaxf(dg, 1.0f);
    float4 res = *(const float4*)(hres + row * HD + c0);
    float y0 = (acc[r][0] + sev.x * w0.x + sev.y * w1.x + dg * bcv.x) * dgi + bnov.x;
    float y1 = (acc[r][1] + sev.x * w0.y + sev.y * w1.y + dg * bcv.y) * dgi + bnov.y;
    float y2 = (acc[r][2] + sev.x * w0.z + sev.y * w1.z + dg * bcv.z) * dgi + bnov.z;
    float y3 = (acc[r][3] + sev.x * w0.w + sev.y * w1.w + dg * bcv.w) * dgi + bnov.w;
    y0 = y0 * sc0 + sh0 + res.x;
    y1 = y1 * sc1 + sh1 + res.y;
    y2 = y2 * sc2 + sh2 + res.z;
    y3 = y3 * sc3 + sh3 + res.w;
    float4 o = make_float4(fmaxf(y0, 0.f), fmaxf(y1, 0.f), fmaxf(y2, 0.f), fmaxf(y3, 0.f));
    *(float4*)(outp + row * HD + c0) = o;
  }
}

// ---------------- pooling + head ----------------

__global__ __launch_bounds__(128) void k_pool(
    const float* __restrict__ h, const int* __restrict__ batch,
    float* __restrict__ meanp, float* __restrict__ maxp) {
  int g = blockIdx.x, d = threadIdx.x;
  int lo = 0, hi = NN;
  while (lo < hi) { int mid = (lo + hi) >> 1; if (batch[mid] < g) lo = mid + 1; else hi = mid; }
  int start = lo;
  lo = start; hi = NN;
  while (lo < hi) { int mid = (lo + hi) >> 1; if (batch[mid] < g + 1) lo = mid + 1; else hi = mid; }
  int end = lo;
  float sum = 0.f, mx = -3.4e38f;
  for (int i = start; i < end; ++i) {
    float val = h[(size_t)i * HD + d];
    sum += val;
    mx = fmaxf(mx, val);
  }
  int cnt = end - start;
  meanp[g * HD + d] = sum / fmaxf((float)cnt, 1.f);
  maxp[g * HD + d] = (cnt > 0) ? mx : 0.f;
}

__global__ __launch_bounds__(256) void k_head(
    const float* __restrict__ meanp, const float* __restrict__ maxp,
    const float* __restrict__ W1, const float* __restrict__ b1,
    const float* __restrict__ g1, const float* __restrict__ bt1,
    const float* __restrict__ m1, const float* __restrict__ v1,
    const float* __restrict__ W2, const float* __restrict__ b2,
    float* __restrict__ outp) {
  __shared__ float z[256];
  __shared__ float s1[128];
  __shared__ float red[256];
  int g = blockIdx.x, t = threadIdx.x;
  z[t] = (t < 128) ? meanp[g * HD + t] : maxp[g * HD + (t - 128)];
  __syncthreads();
  if (t < 128) {
    float y = b1[t];
    for (int k = 0; k < 256; k++) y = fmaf(z[k], W1[k * HD + t], y);
    float sc = g1[t] * rsqrtf(v1[t] + BN_EPS);
    y = (y - m1[t]) * sc + bt1[t];
    s1[t] = fmaxf(y, 0.f);
  }
  __syncthreads();
  float o = b2[t];
  for (int k = 0; k < 128; k++) o = fmaf(s1[k], W2[k * 256 + t], o);
  red[t] = o * o;
  __syncthreads();
  for (int off = 128; off > 0; off >>= 1) {
    if (t < off) red[t] += red[t + off];
    __syncthreads();
  }
  float scale = 1.0f / fmaxf(sqrtf(red[0]), 1e-12f);
  outp[(size_t)g * 256 + t] = o * scale;
}

// ---------------- launch ----------------

extern "C" void kernel_launch(void* const* d_in, const int* in_sizes, int n_in,
                              void* d_out, int out_size, void* d_ws, size_t ws_size,
                              hipStream_t stream) {
  const float* x         = (const float*)d_in[0];
  const float* edge_attr = (const float*)d_in[1];
  const float* We0  = (const float*)d_in[2];
  const float* be0  = (const float*)d_in[3];
  const float* Wn0  = (const float*)d_in[4];
  const float* bno0 = (const float*)d_in[5];
  const float* g0   = (const float*)d_in[6];
  const float* bt0  = (const float*)d_in[7];
  const float* m0   = (const float*)d_in[8];
  const float* v0   = (const float*)d_in[9];
  const float* Wr0  = (const float*)d_in[10];
  const float* br0  = (const float*)d_in[11];
  const float* We_s = (const float*)d_in[12];
  const float* be_s = (const float*)d_in[13];
  const float* Wn_s = (const float*)d_in[14];
  const float* bno_s= (const float*)d_in[15];
  const float* g_s  = (const float*)d_in[16];
  const float* bt_s = (const float*)d_in[17];
  const float* m_s  = (const float*)d_in[18];
  const float* v_s  = (const float*)d_in[19];
  const float* W1   = (const float*)d_in[20];
  const float* b1   = (const float*)d_in[21];
  const float* g1   = (const float*)d_in[22];
  const float* bt1  = (const float*)d_in[23];
  const float* m1   = (const float*)d_in[24];
  const float* v1   = (const float*)d_in[25];
  const float* W2   = (const float*)d_in[26];
  const float* b2   = (const float*)d_in[27];
  const int* edge_index = (const int*)d_in[28];
  const int* batch      = (const int*)d_in[29];
  float* outp = (float*)d_out;

  char* ws = (char*)d_ws;
  size_t off = 0;
  auto alloc = [&](size_t bytes) -> void* {
    void* p = ws + off;
    off = (off + bytes + 255) & ~(size_t)255;
    return p;
  };
  float* hA    = (float*)alloc((size_t)NPAD * HD * 4);
  float* hB    = (float*)alloc((size_t)NPAD * HD * 4);
  float* Sx    = (float*)alloc((size_t)NPAD * 4 * 4);
  float* Se    = (float*)alloc((size_t)NPAD * 2 * 4);
  int*   deg   = (int*)alloc((size_t)NPAD * 4);
  int*   rowptr= (int*)alloc((size_t)(NN + 1) * 4);
  int*   fill  = (int*)alloc((size_t)NN * 4);
  int*   csr   = (int*)alloc((size_t)NE * 4);
  int*   bsum  = (int*)alloc(64 * 4);
  float* cw    = (float*)alloc((size_t)8 * CWS * 4);
  float* meanp = (float*)alloc((size_t)NG * HD * 4);
  float* maxp  = (float*)alloc((size_t)NG * HD * 4);
  (void)ws_size; (void)n_in; (void)in_sizes; (void)out_size;

  hipMemsetAsync(deg, 0, (size_t)NPAD * 4, stream);
  hipMemsetAsync(fill, 0, (size_t)NN * 4, stream);
  hipMemsetAsync(Se, 0, (size_t)NPAD * 2 * 4, stream);
  hipMemsetAsync(Sx, 0, (size_t)NPAD * 4 * 4, stream);

  k_edge_pre<<<(NE + 255) / 256, 256, 0, stream>>>(edge_index, x, edge_attr, deg, Sx, Se);
  k_scanA<<<49, 1024, 0, stream>>>(deg, rowptr, bsum);
  k_scanB<<<1, 1, 0, stream>>>(bsum, 49, rowptr);
  k_scanC<<<49, 1024, 0, stream>>>(rowptr, bsum);
  k_scatter<<<(NE + 255) / 256, 256, 0, stream>>>(edge_index, rowptr, fill, csr);
  k_combine<<<8 * 131, 128, 0, stream>>>(We0, be0, Wn0, We_s, be_s, Wn_s, cw);

  k_layer0<<<NN / 2, 256, 0, stream>>>(x, Sx, Se, deg, cw, bno0, g0, bt0, m0, v0, Wr0, br0, hA);

  float* cur = hA;
  float* oth = hB;
  for (int l = 1; l <= 7; ++l) {
    int li = l - 1;
    k_aggregate<<<(NN + 3) / 4, 256, 0, stream>>>(cur, rowptr, csr, oth);
    k_conv<<<(NN + 31) / 32, 256, 0, stream>>>(oth, cur, oth, cw + (size_t)l * CWS,
        bno_s + li * HD, g_s + li * HD, bt_s + li * HD, m_s + li * HD, v_s + li * HD,
        Se, deg);
    float* t = cur; cur = oth; oth = t;
  }

  k_pool<<<NG, 128, 0, stream>>>(cur, batch, meanp, maxp);
  k_head<<<NG, 256, 0, stream>>>(meanp, maxp, W1, b1, g1, bt1, m1, v1, W2, b2, outp);
}

// Round 3
// 799.729 us; speedup vs baseline: 1.3889x; 1.3889x over previous
//
#include <hip/hip_runtime.h>

constexpr int NN   = 50000;   // nodes
constexpr int NPAD = 50016;   // padded to multiple of 32 for layer tiles
constexpr int NE   = 600000;  // edges
constexpr int NG   = 512;     // graphs
constexpr int HD   = 128;     // hidden
constexpr float BN_EPS = 1e-5f;
constexpr int CWS  = HD*HD + 2*HD + HD;  // per-layer combined-weight slot: Wc[128x128], wce[2x128], bc[128]

// ---------------- preprocessing ----------------

// int-only degree histogram (float atomics removed: they wrote 131 MB via 32B
// sector write-through at the coherence point -> 204 us in round 2)
__global__ __launch_bounds__(256) void k_deg(const int* __restrict__ ei, int* __restrict__ deg) {
  int e = blockIdx.x * 256 + threadIdx.x;
  if (e >= NE) return;
  atomicAdd(&deg[ei[NE + e]], 1);
}

__global__ __launch_bounds__(1024) void k_scanA(const int* __restrict__ deg,
                                                int* __restrict__ rowptr, int* __restrict__ bsum) {
  __shared__ int sm[1024];
  int t = threadIdx.x, b = blockIdx.x;
  int i = b * 1024 + t;
  int v = (i < NN) ? deg[i] : 0;
  sm[t] = v;
  __syncthreads();
  for (int off = 1; off < 1024; off <<= 1) {
    int add = (t >= off) ? sm[t - off] : 0;
    __syncthreads();
    sm[t] += add;
    __syncthreads();
  }
  int incl = sm[t];
  if (i < NN) rowptr[i] = incl - v;   // exclusive within chunk
  if (t == 1023) bsum[b] = incl;
}

__global__ void k_scanB(int* bsum, int nb, int* rowptr) {
  if (threadIdx.x == 0 && blockIdx.x == 0) {
    int acc = 0;
    for (int b = 0; b < nb; b++) { int v = bsum[b]; bsum[b] = acc; acc += v; }
    rowptr[NN] = NE;
  }
}

__global__ __launch_bounds__(1024) void k_scanC(int* rowptr, const int* __restrict__ bsum) {
  int i = blockIdx.x * 1024 + threadIdx.x;
  if (i < NN) rowptr[i] += bsum[blockIdx.x];
}

// scatter src index AND permuted edge_attr into CSR order
__global__ __launch_bounds__(256) void k_scatter(
    const int* __restrict__ ei, const float* __restrict__ ea, const int* __restrict__ rowptr,
    int* __restrict__ fill, int* __restrict__ csr, float* __restrict__ eap) {
  int e = blockIdx.x * 256 + threadIdx.x;
  if (e >= NE) return;
  int s = ei[e], d = ei[NE + e];
  int pos = rowptr[d] + atomicAdd(&fill[d], 1);
  csr[pos] = s;
  *(float2*)(eap + 2 * (size_t)pos) = *(const float2*)(ea + 2 * (size_t)e);
}

// atomic-free per-node sums: Sx[i] = sum x[src], Se[i] = sum edge_attr
__global__ __launch_bounds__(256) void k_node_pre(
    const int* __restrict__ rowptr, const int* __restrict__ csr, const float* __restrict__ eap,
    const float* __restrict__ x, float* __restrict__ Sx, float* __restrict__ Se) {
  int i = blockIdx.x * 256 + threadIdx.x;
  if (i >= NN) return;
  int e0 = rowptr[i], e1 = rowptr[i + 1];
  float4 sx = make_float4(0.f, 0.f, 0.f, 0.f);
  float2 se = make_float2(0.f, 0.f);
  for (int e = e0; e < e1; e++) {
    int s = csr[e];
    float4 xv = *(const float4*)(x + 4 * (size_t)s);
    sx.x += xv.x; sx.y += xv.y; sx.z += xv.z; sx.w += xv.w;
    float2 ev = *(const float2*)(eap + 2 * (size_t)e);
    se.x += ev.x; se.y += ev.y;
  }
  *(float4*)(Sx + 4 * (size_t)i) = sx;
  *(float2*)(Se + 2 * (size_t)i) = se;
}

// combined weights: Wc = We_h @ Wn, wce = We_e @ Wn, bc = be @ Wn
__global__ __launch_bounds__(128) void k_combine(
    const float* __restrict__ We0, const float* __restrict__ be0, const float* __restrict__ Wn0,
    const float* __restrict__ We_s, const float* __restrict__ be_s, const float* __restrict__ Wn_s,
    float* __restrict__ cw) {
  int l = blockIdx.x / 131;
  int r = blockIdx.x % 131;
  int j = threadIdx.x;
  float* slot = cw + (size_t)l * CWS;
  const float* Wn;
  const float* Arow;
  float* dst;
  if (l == 0) {
    Wn = Wn0;
    if (r < 4)       { Arow = We0 + r * HD; dst = slot + r * HD; }
    else if (r < 6)  { Arow = We0 + r * HD; dst = slot + HD * HD + (r - 4) * HD; }
    else if (r == 6) { Arow = be0;          dst = slot + HD * HD + 2 * HD; }
    else return;
  } else {
    int li = l - 1;
    Wn = Wn_s + (size_t)li * HD * HD;
    const float* We = We_s + (size_t)li * 130 * HD;
    if (r < 128)      { Arow = We + r * HD;  dst = slot + r * HD; }
    else if (r < 130) { Arow = We + r * HD;  dst = slot + HD * HD + (r - 128) * HD; }
    else              { Arow = be_s + li * HD; dst = slot + HD * HD + 2 * HD; }
  }
  float acc = 0.f;
  for (int t = 0; t < HD; t++) acc = fmaf(Arow[t], Wn[t * HD + j], acc);
  dst[j] = acc;
}

// ---------------- layer 0 (K=4) ----------------

__global__ __launch_bounds__(256) void k_layer0(
    const float* __restrict__ x, const float* __restrict__ Sx, const float* __restrict__ Se,
    const int* __restrict__ deg, const float* __restrict__ cw0,
    const float* __restrict__ bno0, const float* __restrict__ g0, const float* __restrict__ bt0,
    const float* __restrict__ m0, const float* __restrict__ v0,
    const float* __restrict__ Wr0, const float* __restrict__ br0,
    float* __restrict__ outp) {
  int tid = threadIdx.x;
  int row = blockIdx.x * 2 + (tid >> 7);
  int c = tid & 127;
  const float* Wc0  = cw0;                 // [4][128]
  const float* wce0 = cw0 + HD * HD;       // [2][128]
  const float* bc0  = cw0 + HD * HD + 2 * HD;
  float y = 0.f;
#pragma unroll
  for (int k = 0; k < 4; k++) y = fmaf(Sx[row * 4 + k], Wc0[k * HD + c], y);
  y = fmaf(Se[row * 2 + 0], wce0[c], y);
  y = fmaf(Se[row * 2 + 1], wce0[HD + c], y);
  float dg = (float)deg[row];
  y = fmaf(dg, bc0[c], y);
  float dgi = 1.0f / fmaxf(dg, 1.0f);
  y = y * dgi + bno0[c];
  float sc = g0[c] * rsqrtf(v0[c] + BN_EPS);
  float sh = bt0[c] - m0[c] * sc;
  y = y * sc + sh;
  float r = br0[c];
#pragma unroll
  for (int k = 0; k < 4; k++) r = fmaf(x[row * 4 + k], Wr0[k * HD + c], r);
  outp[(size_t)row * HD + c] = fmaxf(y + r, 0.f);
}

// ---------------- fused layer: aggregate (gather-sum) + GEMM + epilogue ----------------
// LDS = 16 KB (S tile only); weight read direct from global (each element used
// once per block -> LDS staging buys nothing, and occupancy goes 3 -> 8 blk/CU).

__global__ __launch_bounds__(256) void k_layer(
    const float* __restrict__ h, const int* __restrict__ rowptr, const int* __restrict__ csr,
    const float* __restrict__ cwl,
    const float* __restrict__ bno, const float* __restrict__ gam, const float* __restrict__ bet,
    const float* __restrict__ mu, const float* __restrict__ var,
    const float* __restrict__ Se, const int* __restrict__ deg,
    float* __restrict__ outp) {
  __shared__ float St[32 * HD];    // 16 KB
  int tid = threadIdx.x;
  int wid = tid >> 6, lane = tid & 63;
  int rowbase = blockIdx.x * 32;

  // phase A: each wave aggregates 8 rows; lane owns 8 bytes of the 512B row
#pragma unroll
  for (int r8 = 0; r8 < 8; r8++) {
    int lr = wid * 8 + r8;
    int i = __builtin_amdgcn_readfirstlane(rowbase + lr);
    float2 acc = make_float2(0.f, 0.f);
    if (i < NN) {
      int e0 = rowptr[i], e1 = rowptr[i + 1];
      int e = e0;
      for (; e + 4 <= e1; e += 4) {       // 4x MLP on the gather
        int s0 = csr[e], s1 = csr[e + 1], s2 = csr[e + 2], s3 = csr[e + 3];
        float2 v0 = *(const float2*)(h + (size_t)s0 * HD + 2 * lane);
        float2 v1 = *(const float2*)(h + (size_t)s1 * HD + 2 * lane);
        float2 v2 = *(const float2*)(h + (size_t)s2 * HD + 2 * lane);
        float2 v3 = *(const float2*)(h + (size_t)s3 * HD + 2 * lane);
        acc.x += v0.x + v1.x + v2.x + v3.x;
        acc.y += v0.y + v1.y + v2.y + v3.y;
      }
      for (; e < e1; e++) {
        int s = csr[e];
        float2 v = *(const float2*)(h + (size_t)s * HD + 2 * lane);
        acc.x += v.x;
        acc.y += v.y;
      }
    }
    *(float2*)(&St[lr * HD + 2 * lane]) = acc;
  }
  __syncthreads();

  // phase B: [32x128] x [128x128] GEMM, weight streamed from global
  int cg = tid & 31;   // cols cg*4 .. +3
  int rg = tid >> 5;   // rows rg*4 .. +3
  float acc[4][4];
#pragma unroll
  for (int r = 0; r < 4; r++)
#pragma unroll
    for (int c = 0; c < 4; c++) acc[r][c] = 0.f;
  const float4* W4 = (const float4*)cwl;
#pragma unroll 4
  for (int k = 0; k < HD; k++) {
    float4 w = W4[k * 32 + cg];
#pragma unroll
    for (int r = 0; r < 4; r++) {
      float s = St[(rg * 4 + r) * HD + k];
      acc[r][0] = fmaf(s, w.x, acc[r][0]);
      acc[r][1] = fmaf(s, w.y, acc[r][1]);
      acc[r][2] = fmaf(s, w.z, acc[r][2]);
      acc[r][3] = fmaf(s, w.w, acc[r][3]);
    }
  }

  int c0 = cg * 4;
  const float* wce = cwl + HD * HD;
  const float* bcp = cwl + HD * HD + 2 * HD;
  float4 w0   = *(const float4*)(wce + c0);
  float4 w1   = *(const float4*)(wce + HD + c0);
  float4 bcv  = *(const float4*)(bcp + c0);
  float4 bnov = *(const float4*)(bno + c0);
  float4 gv   = *(const float4*)(gam + c0);
  float4 btv  = *(const float4*)(bet + c0);
  float4 mv   = *(const float4*)(mu + c0);
  float4 vv   = *(const float4*)(var + c0);
  float sc0 = gv.x * rsqrtf(vv.x + BN_EPS), sh0 = btv.x - mv.x * sc0;
  float sc1 = gv.y * rsqrtf(vv.y + BN_EPS), sh1 = btv.y - mv.y * sc1;
  float sc2 = gv.z * rsqrtf(vv.z + BN_EPS), sh2 = btv.z - mv.z * sc2;
  float sc3 = gv.w * rsqrtf(vv.w + BN_EPS), sh3 = btv.w - mv.w * sc3;
#pragma unroll
  for (int r = 0; r < 4; r++) {
    size_t row = rowbase + rg * 4 + r;
    float2 sev = *(const float2*)(Se + row * 2);
    float dg = (float)deg[row];
    float dgi = 1.0f / fmaxf(dg, 1.0f);
    float4 res = *(const float4*)(h + row * HD + c0);
    float y0 = (acc[r][0] + sev.x * w0.x + sev.y * w1.x + dg * bcv.x) * dgi + bnov.x;
    float y1 = (acc[r][1] + sev.x * w0.y + sev.y * w1.y + dg * bcv.y) * dgi + bnov.y;
    float y2 = (acc[r][2] + sev.x * w0.z + sev.y * w1.z + dg * bcv.z) * dgi + bnov.z;
    float y3 = (acc[r][3] + sev.x * w0.w + sev.y * w1.w + dg * bcv.w) * dgi + bnov.w;
    y0 = y0 * sc0 + sh0 + res.x;
    y1 = y1 * sc1 + sh1 + res.y;
    y2 = y2 * sc2 + sh2 + res.z;
    y3 = y3 * sc3 + sh3 + res.w;
    float4 o = make_float4(fmaxf(y0, 0.f), fmaxf(y1, 0.f), fmaxf(y2, 0.f), fmaxf(y3, 0.f));
    *(float4*)(outp + row * HD + c0) = o;
  }
}

// ---------------- pooling + head ----------------

__global__ __launch_bounds__(128) void k_pool(
    const float* __restrict__ h, const int* __restrict__ batch,
    float* __restrict__ meanp, float* __restrict__ maxp) {
  int g = blockIdx.x, d = threadIdx.x;
  int lo = 0, hi = NN;
  while (lo < hi) { int mid = (lo + hi) >> 1; if (batch[mid] < g) lo = mid + 1; else hi = mid; }
  int start = lo;
  lo = start; hi = NN;
  while (lo < hi) { int mid = (lo + hi) >> 1; if (batch[mid] < g + 1) lo = mid + 1; else hi = mid; }
  int end = lo;
  float sum = 0.f, mx = -3.4e38f;
  for (int i = start; i < end; ++i) {
    float val = h[(size_t)i * HD + d];
    sum += val;
    mx = fmaxf(mx, val);
  }
  int cnt = end - start;
  meanp[g * HD + d] = sum / fmaxf((float)cnt, 1.f);
  maxp[g * HD + d] = (cnt > 0) ? mx : 0.f;
}

__global__ __launch_bounds__(256) void k_head(
    const float* __restrict__ meanp, const float* __restrict__ maxp,
    const float* __restrict__ W1, const float* __restrict__ b1,
    const float* __restrict__ g1, const float* __restrict__ bt1,
    const float* __restrict__ m1, const float* __restrict__ v1,
    const float* __restrict__ W2, const float* __restrict__ b2,
    float* __restrict__ outp) {
  __shared__ float z[256];
  __shared__ float s1[128];
  __shared__ float red[256];
  int g = blockIdx.x, t = threadIdx.x;
  z[t] = (t < 128) ? meanp[g * HD + t] : maxp[g * HD + (t - 128)];
  __syncthreads();
  if (t < 128) {
    float y = b1[t];
    for (int k = 0; k < 256; k++) y = fmaf(z[k], W1[k * HD + t], y);
    float sc = g1[t] * rsqrtf(v1[t] + BN_EPS);
    y = (y - m1[t]) * sc + bt1[t];
    s1[t] = fmaxf(y, 0.f);
  }
  __syncthreads();
  float o = b2[t];
  for (int k = 0; k < 128; k++) o = fmaf(s1[k], W2[k * 256 + t], o);
  red[t] = o * o;
  __syncthreads();
  for (int off = 128; off > 0; off >>= 1) {
    if (t < off) red[t] += red[t + off];
    __syncthreads();
  }
  float scale = 1.0f / fmaxf(sqrtf(red[0]), 1e-12f);
  outp[(size_t)g * 256 + t] = o * scale;
}

// ---------------- launch ----------------

extern "C" void kernel_launch(void* const* d_in, const int* in_sizes, int n_in,
                              void* d_out, int out_size, void* d_ws, size_t ws_size,
                              hipStream_t stream) {
  const float* x         = (const float*)d_in[0];
  const float* edge_attr = (const float*)d_in[1];
  const float* We0  = (const float*)d_in[2];
  const float* be0  = (const float*)d_in[3];
  const float* Wn0  = (const float*)d_in[4];
  const float* bno0 = (const float*)d_in[5];
  const float* g0   = (const float*)d_in[6];
  const float* bt0  = (const float*)d_in[7];
  const float* m0   = (const float*)d_in[8];
  const float* v0   = (const float*)d_in[9];
  const float* Wr0  = (const float*)d_in[10];
  const float* br0  = (const float*)d_in[11];
  const float* We_s = (const float*)d_in[12];
  const float* be_s = (const float*)d_in[13];
  const float* Wn_s = (const float*)d_in[14];
  const float* bno_s= (const float*)d_in[15];
  const float* g_s  = (const float*)d_in[16];
  const float* bt_s = (const float*)d_in[17];
  const float* m_s  = (const float*)d_in[18];
  const float* v_s  = (const float*)d_in[19];
  const float* W1   = (const float*)d_in[20];
  const float* b1   = (const float*)d_in[21];
  const float* g1   = (const float*)d_in[22];
  const float* bt1  = (const float*)d_in[23];
  const float* m1   = (const float*)d_in[24];
  const float* v1   = (const float*)d_in[25];
  const float* W2   = (const float*)d_in[26];
  const float* b2   = (const float*)d_in[27];
  const int* edge_index = (const int*)d_in[28];
  const int* batch      = (const int*)d_in[29];
  float* outp = (float*)d_out;

  char* ws = (char*)d_ws;
  size_t off = 0;
  auto alloc = [&](size_t bytes) -> void* {
    void* p = ws + off;
    off = (off + bytes + 255) & ~(size_t)255;
    return p;
  };
  float* hA    = (float*)alloc((size_t)NPAD * HD * 4);
  float* hB    = (float*)alloc((size_t)NPAD * HD * 4);
  float* Sx    = (float*)alloc((size_t)NPAD * 4 * 4);
  float* Se    = (float*)alloc((size_t)NPAD * 2 * 4);
  int*   deg   = (int*)alloc((size_t)NPAD * 4);
  int*   rowptr= (int*)alloc((size_t)(NN + 1) * 4);
  int*   fill  = (int*)alloc((size_t)NN * 4);
  int*   csr   = (int*)alloc((size_t)NE * 4);
  float* eap   = (float*)alloc((size_t)NE * 2 * 4);
  int*   bsum  = (int*)alloc(64 * 4);
  float* cw    = (float*)alloc((size_t)8 * CWS * 4);
  float* meanp = (float*)alloc((size_t)NG * HD * 4);
  float* maxp  = (float*)alloc((size_t)NG * HD * 4);
  (void)ws_size; (void)n_in; (void)in_sizes; (void)out_size;

  hipMemsetAsync(deg, 0, (size_t)NPAD * 4, stream);
  hipMemsetAsync(fill, 0, (size_t)NN * 4, stream);
  hipMemsetAsync(Se, 0, (size_t)NPAD * 2 * 4, stream);

  k_deg<<<(NE + 255) / 256, 256, 0, stream>>>(edge_index, deg);
  k_scanA<<<49, 1024, 0, stream>>>(deg, rowptr, bsum);
  k_scanB<<<1, 1, 0, stream>>>(bsum, 49, rowptr);
  k_scanC<<<49, 1024, 0, stream>>>(rowptr, bsum);
  k_scatter<<<(NE + 255) / 256, 256, 0, stream>>>(edge_index, edge_attr, rowptr, fill, csr, eap);
  k_node_pre<<<(NN + 255) / 256, 256, 0, stream>>>(rowptr, csr, eap, x, Sx, Se);
  k_combine<<<8 * 131, 128, 0, stream>>>(We0, be0, Wn0, We_s, be_s, Wn_s, cw);

  k_layer0<<<NN / 2, 256, 0, stream>>>(x, Sx, Se, deg, cw, bno0, g0, bt0, m0, v0, Wr0, br0, hA);

  float* cur = hA;
  float* oth = hB;
  for (int l = 1; l <= 7; ++l) {
    int li = l - 1;
    k_layer<<<NPAD / 32, 256, 0, stream>>>(cur, rowptr, csr, cw + (size_t)l * CWS,
        bno_s + li * HD, g_s + li * HD, bt_s + li * HD, m_s + li * HD, v_s + li * HD,
        Se, deg, oth);
    float* t = cur; cur = oth; oth = t;
  }

  k_pool<<<NG, 128, 0, stream>>>(cur, batch, meanp, maxp);
  k_head<<<NG, 256, 0, stream>>>(meanp, maxp, W1, b1, g1, bt1, m1, v1, W2, b2, outp);
}

// Round 4
// 703.156 us; speedup vs baseline: 1.5797x; 1.1373x over previous
//
#include <hip/hip_runtime.h>
#include <hip/hip_bf16.h>

constexpr int NN   = 50000;   // nodes
constexpr int NPAD = 50016;   // padded to multiple of 32 for layer tiles
constexpr int NE   = 600000;  // edges
constexpr int NG   = 512;     // graphs
constexpr int HD   = 128;     // hidden
constexpr float BN_EPS = 1e-5f;
constexpr int CWS  = HD*HD + 2*HD + HD;  // per-layer combined-weight slot: Wc[128x128], wce[2x128], bc[128]

// pack 2 floats -> 2 bf16 (RNE) in one uint (a=low, b=high)
__device__ inline unsigned bf16pk(float a, float b) {
  unsigned ua = __float_as_uint(a), ub = __float_as_uint(b);
  ua = (ua + 0x7FFFu + ((ua >> 16) & 1u)) >> 16;
  ub = (ub + 0x7FFFu + ((ub >> 16) & 1u)) & 0xFFFF0000u;
  return ua | ub;
}

// ---------------- preprocessing ----------------

// degree histogram; rank[e] = this edge's slot within its dst row (atomic return)
__global__ __launch_bounds__(256) void k_deg(const int* __restrict__ ei,
                                             int* __restrict__ deg, int* __restrict__ rank) {
  int e = blockIdx.x * 256 + threadIdx.x;
  if (e >= NE) return;
  rank[e] = atomicAdd(&deg[ei[NE + e]], 1);
}

__global__ __launch_bounds__(1024) void k_scanA(const int* __restrict__ deg,
                                                int* __restrict__ rowptr, int* __restrict__ bsum) {
  __shared__ int sm[1024];
  int t = threadIdx.x, b = blockIdx.x;
  int i = b * 1024 + t;
  int v = (i < NN) ? deg[i] : 0;
  sm[t] = v;
  __syncthreads();
  for (int off = 1; off < 1024; off <<= 1) {
    int add = (t >= off) ? sm[t - off] : 0;
    __syncthreads();
    sm[t] += add;
    __syncthreads();
  }
  int incl = sm[t];
  if (i < NN) rowptr[i] = incl - v;   // exclusive within chunk
  if (t == 1023) bsum[b] = incl;
}

__global__ void k_scanB(int* bsum, int nb, int* rowptr) {
  if (threadIdx.x == 0 && blockIdx.x == 0) {
    int acc = 0;
    for (int b = 0; b < nb; b++) { int v = bsum[b]; bsum[b] = acc; acc += v; }
    rowptr[NN] = NE;
  }
}

__global__ __launch_bounds__(1024) void k_scanC(int* rowptr, const int* __restrict__ bsum) {
  int i = blockIdx.x * 1024 + threadIdx.x;
  if (i < NN) rowptr[i] += bsum[blockIdx.x];
}

// atomic-free scatter of src index + permuted edge_attr into CSR order
__global__ __launch_bounds__(256) void k_scatter(
    const int* __restrict__ ei, const float* __restrict__ ea, const int* __restrict__ rowptr,
    const int* __restrict__ rank, int* __restrict__ csr, float* __restrict__ eap) {
  int e = blockIdx.x * 256 + threadIdx.x;
  if (e >= NE) return;
  int s = ei[e], d = ei[NE + e];
  int pos = rowptr[d] + rank[e];
  csr[pos] = s;
  *(float2*)(eap + 2 * (size_t)pos) = *(const float2*)(ea + 2 * (size_t)e);
}

// atomic-free per-node sums: Sx[i] = sum x[src], Se[i] = sum edge_attr
__global__ __launch_bounds__(256) void k_node_pre(
    const int* __restrict__ rowptr, const int* __restrict__ csr, const float* __restrict__ eap,
    const float* __restrict__ x, float* __restrict__ Sx, float* __restrict__ Se) {
  int i = blockIdx.x * 256 + threadIdx.x;
  if (i >= NN) return;
  int e0 = rowptr[i], e1 = rowptr[i + 1];
  float4 sx = make_float4(0.f, 0.f, 0.f, 0.f);
  float2 se = make_float2(0.f, 0.f);
  for (int e = e0; e < e1; e++) {
    int s = csr[e];
    float4 xv = *(const float4*)(x + 4 * (size_t)s);
    sx.x += xv.x; sx.y += xv.y; sx.z += xv.z; sx.w += xv.w;
    float2 ev = *(const float2*)(eap + 2 * (size_t)e);
    se.x += ev.x; se.y += ev.y;
  }
  *(float4*)(Sx + 4 * (size_t)i) = sx;
  *(float2*)(Se + 2 * (size_t)i) = se;
}

// combined weights: Wc = We_h @ Wn, wce = We_e @ Wn, bc = be @ Wn
__global__ __launch_bounds__(128) void k_combine(
    const float* __restrict__ We0, const float* __restrict__ be0, const float* __restrict__ Wn0,
    const float* __restrict__ We_s, const float* __restrict__ be_s, const float* __restrict__ Wn_s,
    float* __restrict__ cw) {
  int l = blockIdx.x / 131;
  int r = blockIdx.x % 131;
  int j = threadIdx.x;
  float* slot = cw + (size_t)l * CWS;
  const float* Wn;
  const float* Arow;
  float* dst;
  if (l == 0) {
    Wn = Wn0;
    if (r < 4)       { Arow = We0 + r * HD; dst = slot + r * HD; }
    else if (r < 6)  { Arow = We0 + r * HD; dst = slot + HD * HD + (r - 4) * HD; }
    else if (r == 6) { Arow = be0;          dst = slot + HD * HD + 2 * HD; }
    else return;
  } else {
    int li = l - 1;
    Wn = Wn_s + (size_t)li * HD * HD;
    const float* We = We_s + (size_t)li * 130 * HD;
    if (r < 128)      { Arow = We + r * HD;  dst = slot + r * HD; }
    else if (r < 130) { Arow = We + r * HD;  dst = slot + HD * HD + (r - 128) * HD; }
    else              { Arow = be_s + li * HD; dst = slot + HD * HD + 2 * HD; }
  }
  float acc = 0.f;
  for (int t = 0; t < HD; t++) acc = fmaf(Arow[t], Wn[t * HD + j], acc);
  dst[j] = acc;
}

// ---------------- layer 0 (K=4) ----------------

__global__ __launch_bounds__(256) void k_layer0(
    const float* __restrict__ x, const float* __restrict__ Sx, const float* __restrict__ Se,
    const int* __restrict__ deg, const float* __restrict__ cw0,
    const float* __restrict__ bno0, const float* __restrict__ g0, const float* __restrict__ bt0,
    const float* __restrict__ m0, const float* __restrict__ v0,
    const float* __restrict__ Wr0, const float* __restrict__ br0,
    float* __restrict__ outp, unsigned short* __restrict__ outbf) {
  int tid = threadIdx.x;
  int row = blockIdx.x * 2 + (tid >> 7);
  int c = tid & 127;
  const float* Wc0  = cw0;                 // [4][128]
  const float* wce0 = cw0 + HD * HD;       // [2][128]
  const float* bc0  = cw0 + HD * HD + 2 * HD;
  float y = 0.f;
#pragma unroll
  for (int k = 0; k < 4; k++) y = fmaf(Sx[row * 4 + k], Wc0[k * HD + c], y);
  y = fmaf(Se[row * 2 + 0], wce0[c], y);
  y = fmaf(Se[row * 2 + 1], wce0[HD + c], y);
  float dg = (float)deg[row];
  y = fmaf(dg, bc0[c], y);
  float dgi = 1.0f / fmaxf(dg, 1.0f);
  y = y * dgi + bno0[c];
  float sc = g0[c] * rsqrtf(v0[c] + BN_EPS);
  float sh = bt0[c] - m0[c] * sc;
  y = y * sc + sh;
  float r = br0[c];
#pragma unroll
  for (int k = 0; k < 4; k++) r = fmaf(x[row * 4 + k], Wr0[k * HD + c], r);
  float o = fmaxf(y + r, 0.f);
  outp[(size_t)row * HD + c] = o;
  unsigned u = __float_as_uint(o);
  outbf[(size_t)row * HD + c] = (unsigned short)((u + 0x7FFFu + ((u >> 16) & 1u)) >> 16);
}

// ---------------- fused layer: bf16 gather-sum + f32 GEMM + epilogue ----------------
// Gather table is a bf16 shadow of h (halves the latency-bound random-read bytes);
// accumulation, GEMM, BN, residual all stay f32.

__global__ __launch_bounds__(256) void k_layer(
    const float* __restrict__ h, const unsigned* __restrict__ hbf,
    const int* __restrict__ rowptr, const int* __restrict__ csr,
    const float* __restrict__ cwl,
    const float* __restrict__ bno, const float* __restrict__ gam, const float* __restrict__ bet,
    const float* __restrict__ mu, const float* __restrict__ var,
    const float* __restrict__ Se, const int* __restrict__ deg,
    float* __restrict__ outp, unsigned* __restrict__ outbf) {
  __shared__ float St[32 * HD];    // 16 KB
  int tid = threadIdx.x;
  int wid = tid >> 6, lane = tid & 63;
  int rowbase = blockIdx.x * 32;

  // phase A: each wave aggregates 8 rows; lane owns 2 channels (one uint = 2 bf16)
#pragma unroll
  for (int r8 = 0; r8 < 8; r8++) {
    int lr = wid * 8 + r8;
    int i = __builtin_amdgcn_readfirstlane(rowbase + lr);
    float accx = 0.f, accy = 0.f;
    if (i < NN) {
      int e0 = rowptr[i], e1 = rowptr[i + 1];
      int e = e0;
      for (; e + 4 <= e1; e += 4) {       // 4x MLP on the gather
        int s0 = csr[e], s1 = csr[e + 1], s2 = csr[e + 2], s3 = csr[e + 3];
        unsigned v0 = hbf[(size_t)s0 * 64 + lane];
        unsigned v1 = hbf[(size_t)s1 * 64 + lane];
        unsigned v2 = hbf[(size_t)s2 * 64 + lane];
        unsigned v3 = hbf[(size_t)s3 * 64 + lane];
        accx += __uint_as_float(v0 << 16) + __uint_as_float(v1 << 16)
              + __uint_as_float(v2 << 16) + __uint_as_float(v3 << 16);
        accy += __uint_as_float(v0 & 0xFFFF0000u) + __uint_as_float(v1 & 0xFFFF0000u)
              + __uint_as_float(v2 & 0xFFFF0000u) + __uint_as_float(v3 & 0xFFFF0000u);
      }
      for (; e < e1; e++) {
        unsigned v = hbf[(size_t)csr[e] * 64 + lane];
        accx += __uint_as_float(v << 16);
        accy += __uint_as_float(v & 0xFFFF0000u);
      }
    }
    St[lr * HD + 2 * lane]     = accx;
    St[lr * HD + 2 * lane + 1] = accy;
  }
  __syncthreads();

  // phase B: [32x128] x [128x128] GEMM, weight streamed from global (L2-resident)
  int cg = tid & 31;   // cols cg*4 .. +3
  int rg = tid >> 5;   // rows rg*4 .. +3
  float acc[4][4];
#pragma unroll
  for (int r = 0; r < 4; r++)
#pragma unroll
    for (int c = 0; c < 4; c++) acc[r][c] = 0.f;
  const float4* W4 = (const float4*)cwl;
#pragma unroll 4
  for (int k = 0; k < HD; k++) {
    float4 w = W4[k * 32 + cg];
#pragma unroll
    for (int r = 0; r < 4; r++) {
      float s = St[(rg * 4 + r) * HD + k];
      acc[r][0] = fmaf(s, w.x, acc[r][0]);
      acc[r][1] = fmaf(s, w.y, acc[r][1]);
      acc[r][2] = fmaf(s, w.z, acc[r][2]);
      acc[r][3] = fmaf(s, w.w, acc[r][3]);
    }
  }

  int c0 = cg * 4;
  const float* wce = cwl + HD * HD;
  const float* bcp = cwl + HD * HD + 2 * HD;
  float4 w0   = *(const float4*)(wce + c0);
  float4 w1   = *(const float4*)(wce + HD + c0);
  float4 bcv  = *(const float4*)(bcp + c0);
  float4 bnov = *(const float4*)(bno + c0);
  float4 gv   = *(const float4*)(gam + c0);
  float4 btv  = *(const float4*)(bet + c0);
  float4 mv   = *(const float4*)(mu + c0);
  float4 vv   = *(const float4*)(var + c0);
  float sc0 = gv.x * rsqrtf(vv.x + BN_EPS), sh0 = btv.x - mv.x * sc0;
  float sc1 = gv.y * rsqrtf(vv.y + BN_EPS), sh1 = btv.y - mv.y * sc1;
  float sc2 = gv.z * rsqrtf(vv.z + BN_EPS), sh2 = btv.z - mv.z * sc2;
  float sc3 = gv.w * rsqrtf(vv.w + BN_EPS), sh3 = btv.w - mv.w * sc3;
#pragma unroll
  for (int r = 0; r < 4; r++) {
    size_t row = rowbase + rg * 4 + r;
    float2 sev = *(const float2*)(Se + row * 2);
    float dg = (float)deg[row];
    float dgi = 1.0f / fmaxf(dg, 1.0f);
    float4 res = *(const float4*)(h + row * HD + c0);
    float y0 = (acc[r][0] + sev.x * w0.x + sev.y * w1.x + dg * bcv.x) * dgi + bnov.x;
    float y1 = (acc[r][1] + sev.x * w0.y + sev.y * w1.y + dg * bcv.y) * dgi + bnov.y;
    float y2 = (acc[r][2] + sev.x * w0.z + sev.y * w1.z + dg * bcv.z) * dgi + bnov.z;
    float y3 = (acc[r][3] + sev.x * w0.w + sev.y * w1.w + dg * bcv.w) * dgi + bnov.w;
    y0 = fmaxf(y0 * sc0 + sh0 + res.x, 0.f);
    y1 = fmaxf(y1 * sc1 + sh1 + res.y, 0.f);
    y2 = fmaxf(y2 * sc2 + sh2 + res.z, 0.f);
    y3 = fmaxf(y3 * sc3 + sh3 + res.w, 0.f);
    *(float4*)(outp + row * HD + c0) = make_float4(y0, y1, y2, y3);
    uint2 pk = make_uint2(bf16pk(y0, y1), bf16pk(y2, y3));
    *(uint2*)(outbf + row * 64 + c0 / 2) = pk;
  }
}

// ---------------- pooling + head ----------------

__global__ __launch_bounds__(128) void k_pool(
    const float* __restrict__ h, const int* __restrict__ batch,
    float* __restrict__ meanp, float* __restrict__ maxp) {
  int g = blockIdx.x, d = threadIdx.x;
  int lo = 0, hi = NN;
  while (lo < hi) { int mid = (lo + hi) >> 1; if (batch[mid] < g) lo = mid + 1; else hi = mid; }
  int start = lo;
  lo = start; hi = NN;
  while (lo < hi) { int mid = (lo + hi) >> 1; if (batch[mid] < g + 1) lo = mid + 1; else hi = mid; }
  int end = lo;
  float sum = 0.f, mx = -3.4e38f;
  for (int i = start; i < end; ++i) {
    float val = h[(size_t)i * HD + d];
    sum += val;
    mx = fmaxf(mx, val);
  }
  int cnt = end - start;
  meanp[g * HD + d] = sum / fmaxf((float)cnt, 1.f);
  maxp[g * HD + d] = (cnt > 0) ? mx : 0.f;
}

__global__ __launch_bounds__(256) void k_head(
    const float* __restrict__ meanp, const float* __restrict__ maxp,
    const float* __restrict__ W1, const float* __restrict__ b1,
    const float* __restrict__ g1, const float* __restrict__ bt1,
    const float* __restrict__ m1, const float* __restrict__ v1,
    const float* __restrict__ W2, const float* __restrict__ b2,
    float* __restrict__ outp) {
  __shared__ float z[256];
  __shared__ float s1[128];
  __shared__ float red[256];
  int g = blockIdx.x, t = threadIdx.x;
  z[t] = (t < 128) ? meanp[g * HD + t] : maxp[g * HD + (t - 128)];
  __syncthreads();
  if (t < 128) {
    float y = b1[t];
    for (int k = 0; k < 256; k++) y = fmaf(z[k], W1[k * HD + t], y);
    float sc = g1[t] * rsqrtf(v1[t] + BN_EPS);
    y = (y - m1[t]) * sc + bt1[t];
    s1[t] = fmaxf(y, 0.f);
  }
  __syncthreads();
  float o = b2[t];
  for (int k = 0; k < 128; k++) o = fmaf(s1[k], W2[k * 256 + t], o);
  red[t] = o * o;
  __syncthreads();
  for (int off = 128; off > 0; off >>= 1) {
    if (t < off) red[t] += red[t + off];
    __syncthreads();
  }
  float scale = 1.0f / fmaxf(sqrtf(red[0]), 1e-12f);
  outp[(size_t)g * 256 + t] = o * scale;
}

// ---------------- launch ----------------

extern "C" void kernel_launch(void* const* d_in, const int* in_sizes, int n_in,
                              void* d_out, int out_size, void* d_ws, size_t ws_size,
                              hipStream_t stream) {
  const float* x         = (const float*)d_in[0];
  const float* edge_attr = (const float*)d_in[1];
  const float* We0  = (const float*)d_in[2];
  const float* be0  = (const float*)d_in[3];
  const float* Wn0  = (const float*)d_in[4];
  const float* bno0 = (const float*)d_in[5];
  const float* g0   = (const float*)d_in[6];
  const float* bt0  = (const float*)d_in[7];
  const float* m0   = (const float*)d_in[8];
  const float* v0   = (const float*)d_in[9];
  const float* Wr0  = (const float*)d_in[10];
  const float* br0  = (const float*)d_in[11];
  const float* We_s = (const float*)d_in[12];
  const float* be_s = (const float*)d_in[13];
  const float* Wn_s = (const float*)d_in[14];
  const float* bno_s= (const float*)d_in[15];
  const float* g_s  = (const float*)d_in[16];
  const float* bt_s = (const float*)d_in[17];
  const float* m_s  = (const float*)d_in[18];
  const float* v_s  = (const float*)d_in[19];
  const float* W1   = (const float*)d_in[20];
  const float* b1   = (const float*)d_in[21];
  const float* g1   = (const float*)d_in[22];
  const float* bt1  = (const float*)d_in[23];
  const float* m1   = (const float*)d_in[24];
  const float* v1   = (const float*)d_in[25];
  const float* W2   = (const float*)d_in[26];
  const float* b2   = (const float*)d_in[27];
  const int* edge_index = (const int*)d_in[28];
  const int* batch      = (const int*)d_in[29];
  float* outp = (float*)d_out;

  char* ws = (char*)d_ws;
  size_t off = 0;
  auto alloc = [&](size_t bytes) -> void* {
    void* p = ws + off;
    off = (off + bytes + 255) & ~(size_t)255;
    return p;
  };
  float* hA    = (float*)alloc((size_t)NPAD * HD * 4);
  float* hB    = (float*)alloc((size_t)NPAD * HD * 4);
  unsigned* hAbf = (unsigned*)alloc((size_t)NPAD * HD * 2);
  unsigned* hBbf = (unsigned*)alloc((size_t)NPAD * HD * 2);
  float* Sx    = (float*)alloc((size_t)NPAD * 4 * 4);
  float* Se    = (float*)alloc((size_t)NPAD * 2 * 4);
  int*   deg   = (int*)alloc((size_t)NPAD * 4);
  int*   rowptr= (int*)alloc((size_t)(NN + 1) * 4);
  int*   rank  = (int*)alloc((size_t)NE * 4);
  int*   csr   = (int*)alloc((size_t)NE * 4);
  float* eap   = (float*)alloc((size_t)NE * 2 * 4);
  int*   bsum  = (int*)alloc(64 * 4);
  float* cw    = (float*)alloc((size_t)8 * CWS * 4);
  float* meanp = (float*)alloc((size_t)NG * HD * 4);
  float* maxp  = (float*)alloc((size_t)NG * HD * 4);
  (void)ws_size; (void)n_in; (void)in_sizes; (void)out_size;

  hipMemsetAsync(deg, 0, (size_t)NPAD * 4, stream);
  hipMemsetAsync(Se, 0, (size_t)NPAD * 2 * 4, stream);

  k_deg<<<(NE + 255) / 256, 256, 0, stream>>>(edge_index, deg, rank);
  k_scanA<<<49, 1024, 0, stream>>>(deg, rowptr, bsum);
  k_scanB<<<1, 1, 0, stream>>>(bsum, 49, rowptr);
  k_scanC<<<49, 1024, 0, stream>>>(rowptr, bsum);
  k_scatter<<<(NE + 255) / 256, 256, 0, stream>>>(edge_index, edge_attr, rowptr, rank, csr, eap);
  k_node_pre<<<(NN + 255) / 256, 256, 0, stream>>>(rowptr, csr, eap, x, Sx, Se);
  k_combine<<<8 * 131, 128, 0, stream>>>(We0, be0, Wn0, We_s, be_s, Wn_s, cw);

  k_layer0<<<NN / 2, 256, 0, stream>>>(x, Sx, Se, deg, cw, bno0, g0, bt0, m0, v0, Wr0, br0,
                                       hA, (unsigned short*)hAbf);

  float* cur = hA;        float* oth = hB;
  unsigned* curbf = hAbf; unsigned* othbf = hBbf;
  for (int l = 1; l <= 7; ++l) {
    int li = l - 1;
    k_layer<<<NPAD / 32, 256, 0, stream>>>(cur, curbf, rowptr, csr, cw + (size_t)l * CWS,
        bno_s + li * HD, g_s + li * HD, bt_s + li * HD, m_s + li * HD, v_s + li * HD,
        Se, deg, oth, othbf);
    float* t = cur; cur = oth; oth = t;
    unsigned* tb = curbf; curbf = othbf; othbf = tb;
  }

  k_pool<<<NG, 128, 0, stream>>>(cur, batch, meanp, maxp);
  k_head<<<NG, 256, 0, stream>>>(meanp, maxp, W1, b1, g1, bt1, m1, v1, W2, b2, outp);
}

// Round 5
// 648.865 us; speedup vs baseline: 1.7119x; 1.0837x over previous
//
#include <hip/hip_runtime.h>
#include <hip/hip_bf16.h>

constexpr int NN   = 50000;   // nodes
constexpr int NPAD = 50016;   // padded to multiple of 32 for layer tiles
constexpr int NE   = 600000;  // edges
constexpr int NG   = 512;     // graphs
constexpr int HD   = 128;     // hidden
constexpr float BN_EPS = 1e-5f;
constexpr int CWS  = HD*HD + 2*HD + HD;  // per-layer combined-weight slot: Wc[128x128], wce[2x128], bc[128]

// pack 2 floats -> 2 bf16 (RNE) in one uint (a=low, b=high)
__device__ inline unsigned bf16pk(float a, float b) {
  unsigned ua = __float_as_uint(a), ub = __float_as_uint(b);
  ua = (ua + 0x7FFFu + ((ua >> 16) & 1u)) >> 16;
  ub = (ub + 0x7FFFu + ((ub >> 16) & 1u)) & 0xFFFF0000u;
  return ua | ub;
}

// ---------------- preprocessing ----------------

// degree histogram; rank[e] = this edge's slot within its dst row (atomic return)
__global__ __launch_bounds__(256) void k_deg(const int* __restrict__ ei,
                                             int* __restrict__ deg, int* __restrict__ rank) {
  int e = blockIdx.x * 256 + threadIdx.x;
  if (e >= NE) return;
  rank[e] = atomicAdd(&deg[ei[NE + e]], 1);
}

__global__ __launch_bounds__(1024) void k_scanA(const int* __restrict__ deg,
                                                int* __restrict__ rowptr, int* __restrict__ bsum) {
  __shared__ int sm[1024];
  int t = threadIdx.x, b = blockIdx.x;
  int i = b * 1024 + t;
  int v = (i < NN) ? deg[i] : 0;
  sm[t] = v;
  __syncthreads();
  for (int off = 1; off < 1024; off <<= 1) {
    int add = (t >= off) ? sm[t - off] : 0;
    __syncthreads();
    sm[t] += add;
    __syncthreads();
  }
  int incl = sm[t];
  if (i < NN) rowptr[i] = incl - v;   // exclusive within chunk
  if (t == 1023) bsum[b] = incl;
}

// scanB folded in: each block serially prefixes the 49 chunk sums itself
__global__ __launch_bounds__(1024) void k_scanC(int* rowptr, const int* __restrict__ bsum) {
  __shared__ int base;
  int b = blockIdx.x;
  if (threadIdx.x == 0) {
    int acc = 0;
    for (int j = 0; j < b; j++) acc += bsum[j];
    base = acc;
    if (b == 0) rowptr[NN] = NE;
  }
  __syncthreads();
  int i = b * 1024 + threadIdx.x;
  if (i < NN) rowptr[i] += base;
}

// atomic-free scatter of src index + permuted edge_attr into CSR order
__global__ __launch_bounds__(256) void k_scatter(
    const int* __restrict__ ei, const float* __restrict__ ea, const int* __restrict__ rowptr,
    const int* __restrict__ rank, int* __restrict__ csr, float* __restrict__ eap) {
  int e = blockIdx.x * 256 + threadIdx.x;
  if (e >= NE) return;
  int s = ei[e], d = ei[NE + e];
  int pos = rowptr[d] + rank[e];
  csr[pos] = s;
  *(float2*)(eap + 2 * (size_t)pos) = *(const float2*)(ea + 2 * (size_t)e);
}

// atomic-free per-node sums: Sx[i] = sum x[src], Se[i] = sum edge_attr
__global__ __launch_bounds__(256) void k_node_pre(
    const int* __restrict__ rowptr, const int* __restrict__ csr, const float* __restrict__ eap,
    const float* __restrict__ x, float* __restrict__ Sx, float* __restrict__ Se) {
  int i = blockIdx.x * 256 + threadIdx.x;
  if (i >= NN) return;
  int e0 = rowptr[i], e1 = rowptr[i + 1];
  float4 sx = make_float4(0.f, 0.f, 0.f, 0.f);
  float2 se = make_float2(0.f, 0.f);
  for (int e = e0; e < e1; e++) {
    int s = csr[e];
    float4 xv = *(const float4*)(x + 4 * (size_t)s);
    sx.x += xv.x; sx.y += xv.y; sx.z += xv.z; sx.w += xv.w;
    float2 ev = *(const float2*)(eap + 2 * (size_t)e);
    se.x += ev.x; se.y += ev.y;
  }
  *(float4*)(Sx + 4 * (size_t)i) = sx;
  *(float2*)(Se + 2 * (size_t)i) = se;
}

// combined weights: Wc = We_h @ Wn, wce = We_e @ Wn, bc = be @ Wn
__global__ __launch_bounds__(128) void k_combine(
    const float* __restrict__ We0, const float* __restrict__ be0, const float* __restrict__ Wn0,
    const float* __restrict__ We_s, const float* __restrict__ be_s, const float* __restrict__ Wn_s,
    float* __restrict__ cw) {
  int l = blockIdx.x / 131;
  int r = blockIdx.x % 131;
  int j = threadIdx.x;
  float* slot = cw + (size_t)l * CWS;
  const float* Wn;
  const float* Arow;
  float* dst;
  if (l == 0) {
    Wn = Wn0;
    if (r < 4)       { Arow = We0 + r * HD; dst = slot + r * HD; }
    else if (r < 6)  { Arow = We0 + r * HD; dst = slot + HD * HD + (r - 4) * HD; }
    else if (r == 6) { Arow = be0;          dst = slot + HD * HD + 2 * HD; }
    else return;
  } else {
    int li = l - 1;
    Wn = Wn_s + (size_t)li * HD * HD;
    const float* We = We_s + (size_t)li * 130 * HD;
    if (r < 128)      { Arow = We + r * HD;  dst = slot + r * HD; }
    else if (r < 130) { Arow = We + r * HD;  dst = slot + HD * HD + (r - 128) * HD; }
    else              { Arow = be_s + li * HD; dst = slot + HD * HD + 2 * HD; }
  }
  float acc = 0.f;
  for (int t = 0; t < HD; t++) acc = fmaf(Arow[t], Wn[t * HD + j], acc);
  dst[j] = acc;
}

// ---------------- layer 0 (K=4) ----------------

__global__ __launch_bounds__(256) void k_layer0(
    const float* __restrict__ x, const float* __restrict__ Sx, const float* __restrict__ Se,
    const int* __restrict__ deg, const float* __restrict__ cw0,
    const float* __restrict__ bno0, const float* __restrict__ g0, const float* __restrict__ bt0,
    const float* __restrict__ m0, const float* __restrict__ v0,
    const float* __restrict__ Wr0, const float* __restrict__ br0,
    float* __restrict__ outp, unsigned short* __restrict__ outbf) {
  int tid = threadIdx.x;
  int row = blockIdx.x * 2 + (tid >> 7);
  int c = tid & 127;
  const float* Wc0  = cw0;                 // [4][128]
  const float* wce0 = cw0 + HD * HD;       // [2][128]
  const float* bc0  = cw0 + HD * HD + 2 * HD;
  float y = 0.f;
#pragma unroll
  for (int k = 0; k < 4; k++) y = fmaf(Sx[row * 4 + k], Wc0[k * HD + c], y);
  y = fmaf(Se[row * 2 + 0], wce0[c], y);
  y = fmaf(Se[row * 2 + 1], wce0[HD + c], y);
  float dg = (float)deg[row];
  y = fmaf(dg, bc0[c], y);
  float dgi = 1.0f / fmaxf(dg, 1.0f);
  y = y * dgi + bno0[c];
  float sc = g0[c] * rsqrtf(v0[c] + BN_EPS);
  float sh = bt0[c] - m0[c] * sc;
  y = y * sc + sh;
  float r = br0[c];
#pragma unroll
  for (int k = 0; k < 4; k++) r = fmaf(x[row * 4 + k], Wr0[k * HD + c], r);
  float o = fmaxf(y + r, 0.f);
  outp[(size_t)row * HD + c] = o;
  unsigned u = __float_as_uint(o);
  outbf[(size_t)row * HD + c] = (unsigned short)((u + 0x7FFFu + ((u >> 16) & 1u)) >> 16);
}

// ---------------- fused layer: dual-edge bf16 gather + f32 GEMM + epilogue ----------------
// Gather: wave split into two 32-lane halves; half p walks CSR slots e0+p, e0+p+2, ...
// Each lane loads uint2 (4 bf16 channels) -> one wave instruction covers 2 edges
// (512 B, 8 cache lines): 2x in-flight lines vs single-edge, 2x fewer issue rounds.
// Cross-half combine via __shfl_xor(...,32). Accum/GEMM/BN/residual stay f32.

__global__ __launch_bounds__(256, 6) void k_layer(
    const float* __restrict__ h, const unsigned* __restrict__ hbf,
    const int* __restrict__ rowptr, const int* __restrict__ csr,
    const float* __restrict__ cwl,
    const float* __restrict__ bno, const float* __restrict__ gam, const float* __restrict__ bet,
    const float* __restrict__ mu, const float* __restrict__ var,
    const float* __restrict__ Se, const int* __restrict__ deg,
    float* __restrict__ outp, unsigned* __restrict__ outbf) {
  __shared__ float St[32 * HD];    // 16 KB
  int tid = threadIdx.x;
  int wid = tid >> 6, lane = tid & 63;
  int half = lane >> 5, l5 = lane & 31;   // half-wave edge parity; l5 owns channels l5*4..+3
  int rowbase = blockIdx.x * 32;
  const uint2* hb2 = (const uint2*)hbf;   // row = 32 uint2 = 256 B

#pragma unroll
  for (int r8 = 0; r8 < 8; r8++) {
    int lr = wid * 8 + r8;
    int i = __builtin_amdgcn_readfirstlane(rowbase + lr);
    float a0 = 0.f, a1 = 0.f, a2 = 0.f, a3 = 0.f;
    if (i < NN) {
      int e0 = rowptr[i], e1 = rowptr[i + 1];
      int e = e0 + half;
      for (; e + 6 < e1; e += 8) {        // 4 pairs in flight = 8 edges
        int s0 = csr[e], s1 = csr[e + 2], s2 = csr[e + 4], s3 = csr[e + 6];
        uint2 v0 = hb2[(size_t)s0 * 32 + l5];
        uint2 v1 = hb2[(size_t)s1 * 32 + l5];
        uint2 v2 = hb2[(size_t)s2 * 32 + l5];
        uint2 v3 = hb2[(size_t)s3 * 32 + l5];
        a0 += __uint_as_float(v0.x << 16) + __uint_as_float(v1.x << 16)
            + __uint_as_float(v2.x << 16) + __uint_as_float(v3.x << 16);
        a1 += __uint_as_float(v0.x & 0xFFFF0000u) + __uint_as_float(v1.x & 0xFFFF0000u)
            + __uint_as_float(v2.x & 0xFFFF0000u) + __uint_as_float(v3.x & 0xFFFF0000u);
        a2 += __uint_as_float(v0.y << 16) + __uint_as_float(v1.y << 16)
            + __uint_as_float(v2.y << 16) + __uint_as_float(v3.y << 16);
        a3 += __uint_as_float(v0.y & 0xFFFF0000u) + __uint_as_float(v1.y & 0xFFFF0000u)
            + __uint_as_float(v2.y & 0xFFFF0000u) + __uint_as_float(v3.y & 0xFFFF0000u);
      }
      for (; e < e1; e += 2) {
        uint2 v = hb2[(size_t)csr[e] * 32 + l5];
        a0 += __uint_as_float(v.x << 16);
        a1 += __uint_as_float(v.x & 0xFFFF0000u);
        a2 += __uint_as_float(v.y << 16);
        a3 += __uint_as_float(v.y & 0xFFFF0000u);
      }
    }
    a0 += __shfl_xor(a0, 32);
    a1 += __shfl_xor(a1, 32);
    a2 += __shfl_xor(a2, 32);
    a3 += __shfl_xor(a3, 32);
    if (half == 0) *(float4*)&St[lr * HD + l5 * 4] = make_float4(a0, a1, a2, a3);
  }
  __syncthreads();

  // phase B: [32x128] x [128x128] GEMM, weight streamed from global (L2-resident)
  int cg = tid & 31;   // cols cg*4 .. +3
  int rg = tid >> 5;   // rows rg*4 .. +3
  float acc[4][4];
#pragma unroll
  for (int r = 0; r < 4; r++)
#pragma unroll
    for (int c = 0; c < 4; c++) acc[r][c] = 0.f;
  const float4* W4 = (const float4*)cwl;
#pragma unroll 4
  for (int k = 0; k < HD; k++) {
    float4 w = W4[k * 32 + cg];
#pragma unroll
    for (int r = 0; r < 4; r++) {
      float s = St[(rg * 4 + r) * HD + k];
      acc[r][0] = fmaf(s, w.x, acc[r][0]);
      acc[r][1] = fmaf(s, w.y, acc[r][1]);
      acc[r][2] = fmaf(s, w.z, acc[r][2]);
      acc[r][3] = fmaf(s, w.w, acc[r][3]);
    }
  }

  int c0 = cg * 4;
  const float* wce = cwl + HD * HD;
  const float* bcp = cwl + HD * HD + 2 * HD;
  float4 w0   = *(const float4*)(wce + c0);
  float4 w1   = *(const float4*)(wce + HD + c0);
  float4 bcv  = *(const float4*)(bcp + c0);
  float4 bnov = *(const float4*)(bno + c0);
  float4 gv   = *(const float4*)(gam + c0);
  float4 btv  = *(const float4*)(bet + c0);
  float4 mv   = *(const float4*)(mu + c0);
  float4 vv   = *(const float4*)(var + c0);
  float sc0 = gv.x * rsqrtf(vv.x + BN_EPS), sh0 = btv.x - mv.x * sc0;
  float sc1 = gv.y * rsqrtf(vv.y + BN_EPS), sh1 = btv.y - mv.y * sc1;
  float sc2 = gv.z * rsqrtf(vv.z + BN_EPS), sh2 = btv.z - mv.z * sc2;
  float sc3 = gv.w * rsqrtf(vv.w + BN_EPS), sh3 = btv.w - mv.w * sc3;
#pragma unroll
  for (int r = 0; r < 4; r++) {
    size_t row = rowbase + rg * 4 + r;
    float2 sev = *(const float2*)(Se + row * 2);
    float dg = (float)deg[row];
    float dgi = 1.0f / fmaxf(dg, 1.0f);
    float4 res = *(const float4*)(h + row * HD + c0);
    float y0 = (acc[r][0] + sev.x * w0.x + sev.y * w1.x + dg * bcv.x) * dgi + bnov.x;
    float y1 = (acc[r][1] + sev.x * w0.y + sev.y * w1.y + dg * bcv.y) * dgi + bnov.y;
    float y2 = (acc[r][2] + sev.x * w0.z + sev.y * w1.z + dg * bcv.z) * dgi + bnov.z;
    float y3 = (acc[r][3] + sev.x * w0.w + sev.y * w1.w + dg * bcv.w) * dgi + bnov.w;
    y0 = fmaxf(y0 * sc0 + sh0 + res.x, 0.f);
    y1 = fmaxf(y1 * sc1 + sh1 + res.y, 0.f);
    y2 = fmaxf(y2 * sc2 + sh2 + res.z, 0.f);
    y3 = fmaxf(y3 * sc3 + sh3 + res.w, 0.f);
    *(float4*)(outp + row * HD + c0) = make_float4(y0, y1, y2, y3);
    uint2 pk = make_uint2(bf16pk(y0, y1), bf16pk(y2, y3));
    *(uint2*)(outbf + row * 64 + c0 / 2) = pk;
  }
}

// ---------------- pooling + head ----------------

__global__ __launch_bounds__(512) void k_pool(
    const float* __restrict__ h, const int* __restrict__ batch,
    float* __restrict__ meanp, float* __restrict__ maxp) {
  __shared__ float ssum[512], smax[512];
  int g = blockIdx.x, t = threadIdx.x;
  int d = t & 127, sub = t >> 7;   // 4-way row split
  int lo = 0, hi = NN;
  while (lo < hi) { int mid = (lo + hi) >> 1; if (batch[mid] < g) lo = mid + 1; else hi = mid; }
  int start = lo;
  lo = start; hi = NN;
  while (lo < hi) { int mid = (lo + hi) >> 1; if (batch[mid] < g + 1) lo = mid + 1; else hi = mid; }
  int end = lo;
  float sum = 0.f, mx = -3.4e38f;
  for (int i = start + sub; i < end; i += 4) {
    float val = h[(size_t)i * HD + d];
    sum += val;
    mx = fmaxf(mx, val);
  }
  ssum[t] = sum; smax[t] = mx;
  __syncthreads();
  if (sub == 0) {
    sum = ssum[t] + ssum[t + 128] + ssum[t + 256] + ssum[t + 384];
    mx = fmaxf(fmaxf(smax[t], smax[t + 128]), fmaxf(smax[t + 256], smax[t + 384]));
    int cnt = end - start;
    meanp[g * HD + d] = sum / fmaxf((float)cnt, 1.f);
    maxp[g * HD + d] = (cnt > 0) ? mx : 0.f;
  }
}

__global__ __launch_bounds__(256) void k_head(
    const float* __restrict__ meanp, const float* __restrict__ maxp,
    const float* __restrict__ W1, const float* __restrict__ b1,
    const float* __restrict__ g1, const float* __restrict__ bt1,
    const float* __restrict__ m1, const float* __restrict__ v1,
    const float* __restrict__ W2, const float* __restrict__ b2,
    float* __restrict__ outp) {
  __shared__ float z[256];
  __shared__ float s1[128];
  __shared__ float red[256];
  int g = blockIdx.x, t = threadIdx.x;
  z[t] = (t < 128) ? meanp[g * HD + t] : maxp[g * HD + (t - 128)];
  __syncthreads();
  if (t < 128) {
    float y = b1[t];
    for (int k = 0; k < 256; k++) y = fmaf(z[k], W1[k * HD + t], y);
    float sc = g1[t] * rsqrtf(v1[t] + BN_EPS);
    y = (y - m1[t]) * sc + bt1[t];
    s1[t] = fmaxf(y, 0.f);
  }
  __syncthreads();
  float o = b2[t];
  for (int k = 0; k < 128; k++) o = fmaf(s1[k], W2[k * 256 + t], o);
  red[t] = o * o;
  __syncthreads();
  for (int off = 128; off > 0; off >>= 1) {
    if (t < off) red[t] += red[t + off];
    __syncthreads();
  }
  float scale = 1.0f / fmaxf(sqrtf(red[0]), 1e-12f);
  outp[(size_t)g * 256 + t] = o * scale;
}

// ---------------- launch ----------------

extern "C" void kernel_launch(void* const* d_in, const int* in_sizes, int n_in,
                              void* d_out, int out_size, void* d_ws, size_t ws_size,
                              hipStream_t stream) {
  const float* x         = (const float*)d_in[0];
  const float* edge_attr = (const float*)d_in[1];
  const float* We0  = (const float*)d_in[2];
  const float* be0  = (const float*)d_in[3];
  const float* Wn0  = (const float*)d_in[4];
  const float* bno0 = (const float*)d_in[5];
  const float* g0   = (const float*)d_in[6];
  const float* bt0  = (const float*)d_in[7];
  const float* m0   = (const float*)d_in[8];
  const float* v0   = (const float*)d_in[9];
  const float* Wr0  = (const float*)d_in[10];
  const float* br0  = (const float*)d_in[11];
  const float* We_s = (const float*)d_in[12];
  const float* be_s = (const float*)d_in[13];
  const float* Wn_s = (const float*)d_in[14];
  const float* bno_s= (const float*)d_in[15];
  const float* g_s  = (const float*)d_in[16];
  const float* bt_s = (const float*)d_in[17];
  const float* m_s  = (const float*)d_in[18];
  const float* v_s  = (const float*)d_in[19];
  const float* W1   = (const float*)d_in[20];
  const float* b1   = (const float*)d_in[21];
  const float* g1   = (const float*)d_in[22];
  const float* bt1  = (const float*)d_in[23];
  const float* m1   = (const float*)d_in[24];
  const float* v1   = (const float*)d_in[25];
  const float* W2   = (const float*)d_in[26];
  const float* b2   = (const float*)d_in[27];
  const int* edge_index = (const int*)d_in[28];
  const int* batch      = (const int*)d_in[29];
  float* outp = (float*)d_out;

  char* ws = (char*)d_ws;
  size_t off = 0;
  auto alloc = [&](size_t bytes) -> void* {
    void* p = ws + off;
    off = (off + bytes + 255) & ~(size_t)255;
    return p;
  };
  float* hA    = (float*)alloc((size_t)NPAD * HD * 4);
  float* hB    = (float*)alloc((size_t)NPAD * HD * 4);
  unsigned* hAbf = (unsigned*)alloc((size_t)NPAD * HD * 2);
  unsigned* hBbf = (unsigned*)alloc((size_t)NPAD * HD * 2);
  float* Sx    = (float*)alloc((size_t)NPAD * 4 * 4);
  float* Se    = (float*)alloc((size_t)NPAD * 2 * 4);
  int*   deg   = (int*)alloc((size_t)NPAD * 4);
  int*   rowptr= (int*)alloc((size_t)(NN + 1) * 4);
  int*   rank  = (int*)alloc((size_t)NE * 4);
  int*   csr   = (int*)alloc((size_t)NE * 4);
  float* eap   = (float*)alloc((size_t)NE * 2 * 4);
  int*   bsum  = (int*)alloc(64 * 4);
  float* cw    = (float*)alloc((size_t)8 * CWS * 4);
  float* meanp = (float*)alloc((size_t)NG * HD * 4);
  float* maxp  = (float*)alloc((size_t)NG * HD * 4);
  (void)ws_size; (void)n_in; (void)in_sizes; (void)out_size;

  hipMemsetAsync(deg, 0, (size_t)NPAD * 4, stream);
  hipMemsetAsync(Se, 0, (size_t)NPAD * 2 * 4, stream);

  k_deg<<<(NE + 255) / 256, 256, 0, stream>>>(edge_index, deg, rank);
  k_scanA<<<49, 1024, 0, stream>>>(deg, rowptr, bsum);
  k_scanC<<<49, 1024, 0, stream>>>(rowptr, bsum);
  k_scatter<<<(NE + 255) / 256, 256, 0, stream>>>(edge_index, edge_attr, rowptr, rank, csr, eap);
  k_node_pre<<<(NN + 255) / 256, 256, 0, stream>>>(rowptr, csr, eap, x, Sx, Se);
  k_combine<<<8 * 131, 128, 0, stream>>>(We0, be0, Wn0, We_s, be_s, Wn_s, cw);

  k_layer0<<<NN / 2, 256, 0, stream>>>(x, Sx, Se, deg, cw, bno0, g0, bt0, m0, v0, Wr0, br0,
                                       hA, (unsigned short*)hAbf);

  float* cur = hA;        float* oth = hB;
  unsigned* curbf = hAbf; unsigned* othbf = hBbf;
  for (int l = 1; l <= 7; ++l) {
    int li = l - 1;
    k_layer<<<NPAD / 32, 256, 0, stream>>>(cur, curbf, rowptr, csr, cw + (size_t)l * CWS,
        bno_s + li * HD, g_s + li * HD, bt_s + li * HD, m_s + li * HD, v_s + li * HD,
        Se, deg, oth, othbf);
    float* t = cur; cur = oth; oth = t;
    unsigned* tb = curbf; curbf = othbf; othbf = tb;
  }

  k_pool<<<NG, 512, 0, stream>>>(cur, batch, meanp, maxp);
  k_head<<<NG, 256, 0, stream>>>(meanp, maxp, W1, b1, g1, bt1, m1, v1, W2, b2, outp);
}

// Round 6
// 590.983 us; speedup vs baseline: 1.8795x; 1.0979x over previous
//
#include <hip/hip_runtime.h>
#include <hip/hip_bf16.h>

constexpr int NN   = 50000;   // nodes
constexpr int NPAD = 50016;   // padded to multiple of 32 for layer tiles
constexpr int NE   = 600000;  // edges
constexpr int NG   = 512;     // graphs
constexpr int HD   = 128;     // hidden
constexpr float BN_EPS = 1e-5f;
constexpr int CWS  = HD*HD + 2*HD + HD;  // per-layer f32 slot: Wc[128x128], wce[2x128], bc[128]
constexpr int WMF_L = 2*4*4*128*8;       // per-layer split-weight table (ushorts): [hi|lo][ks][ksub][col][8]

typedef __attribute__((ext_vector_type(8))) short bf16x8;
typedef __attribute__((ext_vector_type(4))) float f32x4;

__device__ inline unsigned short bf16rne(float v) {
  unsigned u = __float_as_uint(v);
  return (unsigned short)((u + 0x7FFFu + ((u >> 16) & 1u)) >> 16);
}
// split f32 into hi+lo bf16 (v ~= hi + lo, error ~2^-18 relative)
__device__ inline void bfsplit(float v, unsigned short& h, unsigned short& l) {
  unsigned short hb = bf16rne(v);
  float hf = __uint_as_float((unsigned)hb << 16);
  l = bf16rne(v - hf);
  h = hb;
}

// ---------------- preprocessing ----------------

__global__ __launch_bounds__(256) void k_deg(const int* __restrict__ ei,
                                             int* __restrict__ deg, int* __restrict__ rank) {
  int e = blockIdx.x * 256 + threadIdx.x;
  if (e >= NE) return;
  rank[e] = atomicAdd(&deg[ei[NE + e]], 1);
}

__global__ __launch_bounds__(1024) void k_scanA(const int* __restrict__ deg,
                                                int* __restrict__ rowptr, int* __restrict__ bsum) {
  __shared__ int sm[1024];
  int t = threadIdx.x, b = blockIdx.x;
  int i = b * 1024 + t;
  int v = (i < NN) ? deg[i] : 0;
  sm[t] = v;
  __syncthreads();
  for (int off = 1; off < 1024; off <<= 1) {
    int add = (t >= off) ? sm[t - off] : 0;
    __syncthreads();
    sm[t] += add;
    __syncthreads();
  }
  int incl = sm[t];
  if (i < NN) rowptr[i] = incl - v;   // exclusive within chunk
  if (t == 1023) bsum[b] = incl;
}

// scanB folded in: each block serially prefixes the 49 chunk sums itself
__global__ __launch_bounds__(1024) void k_scanC(int* rowptr, const int* __restrict__ bsum) {
  __shared__ int base;
  int b = blockIdx.x;
  if (threadIdx.x == 0) {
    int acc = 0;
    for (int j = 0; j < b; j++) acc += bsum[j];
    base = acc;
    if (b == 0) rowptr[NN] = NE;
  }
  __syncthreads();
  int i = b * 1024 + threadIdx.x;
  if (i < NN) rowptr[i] += base;
}

__global__ __launch_bounds__(256) void k_scatter(
    const int* __restrict__ ei, const float* __restrict__ ea, const int* __restrict__ rowptr,
    const int* __restrict__ rank, int* __restrict__ csr, float* __restrict__ eap) {
  int e = blockIdx.x * 256 + threadIdx.x;
  if (e >= NE) return;
  int s = ei[e], d = ei[NE + e];
  int pos = rowptr[d] + rank[e];
  csr[pos] = s;
  *(float2*)(eap + 2 * (size_t)pos) = *(const float2*)(ea + 2 * (size_t)e);
}

__global__ __launch_bounds__(256) void k_node_pre(
    const int* __restrict__ rowptr, const int* __restrict__ csr, const float* __restrict__ eap,
    const float* __restrict__ x, float* __restrict__ Sx, float* __restrict__ Se) {
  int i = blockIdx.x * 256 + threadIdx.x;
  if (i >= NN) return;
  int e0 = rowptr[i], e1 = rowptr[i + 1];
  float4 sx = make_float4(0.f, 0.f, 0.f, 0.f);
  float2 se = make_float2(0.f, 0.f);
  for (int e = e0; e < e1; e++) {
    int s = csr[e];
    float4 xv = *(const float4*)(x + 4 * (size_t)s);
    sx.x += xv.x; sx.y += xv.y; sx.z += xv.z; sx.w += xv.w;
    float2 ev = *(const float2*)(eap + 2 * (size_t)e);
    se.x += ev.x; se.y += ev.y;
  }
  *(float4*)(Sx + 4 * (size_t)i) = sx;
  *(float2*)(Se + 2 * (size_t)i) = se;
}

// combined weights: Wc = We_h @ Wn (f32), plus split-bf16 MFMA tables for layers 1..7.
// MFMA B-frag layout: lane l holds W[k][col] for col=l&15(+16*nt), k=ks*32+(l>>4)*8+j.
__global__ __launch_bounds__(128) void k_combine(
    const float* __restrict__ We0, const float* __restrict__ be0, const float* __restrict__ Wn0,
    const float* __restrict__ We_s, const float* __restrict__ be_s, const float* __restrict__ Wn_s,
    float* __restrict__ cw, unsigned short* __restrict__ wmf) {
  int l = blockIdx.x / 131;
  int r = blockIdx.x % 131;
  int j = threadIdx.x;
  float* slot = cw + (size_t)l * CWS;
  const float* Wn;
  const float* Arow;
  float* dst;
  if (l == 0) {
    Wn = Wn0;
    if (r < 4)       { Arow = We0 + r * HD; dst = slot + r * HD; }
    else if (r < 6)  { Arow = We0 + r * HD; dst = slot + HD * HD + (r - 4) * HD; }
    else if (r == 6) { Arow = be0;          dst = slot + HD * HD + 2 * HD; }
    else return;
  } else {
    int li = l - 1;
    Wn = Wn_s + (size_t)li * HD * HD;
    const float* We = We_s + (size_t)li * 130 * HD;
    if (r < 128)      { Arow = We + r * HD;  dst = slot + r * HD; }
    else if (r < 130) { Arow = We + r * HD;  dst = slot + HD * HD + (r - 128) * HD; }
    else              { Arow = be_s + li * HD; dst = slot + HD * HD + 2 * HD; }
  }
  float acc = 0.f;
  for (int t = 0; t < HD; t++) acc = fmaf(Arow[t], Wn[t * HD + j], acc);
  dst[j] = acc;
  if (l >= 1 && r < 128) {
    unsigned short hb, lb;
    bfsplit(acc, hb, lb);
    size_t wbase = (size_t)(l - 1) * WMF_L;
    int kb = r >> 5, ks2 = (r >> 3) & 3, jj = r & 7;  // k = r
    size_t o = (size_t)((kb * 4 + ks2) * 128 + j) * 8 + jj;
    wmf[wbase + o] = hb;
    wmf[wbase + WMF_L / 2 + o] = lb;
  }
}

// ---------------- layer 0 (K=4) ----------------

__global__ __launch_bounds__(256) void k_layer0(
    const float* __restrict__ x, const float* __restrict__ Sx, const float* __restrict__ Se,
    const int* __restrict__ deg, const float* __restrict__ cw0,
    const float* __restrict__ bno0, const float* __restrict__ g0, const float* __restrict__ bt0,
    const float* __restrict__ m0, const float* __restrict__ v0,
    const float* __restrict__ Wr0, const float* __restrict__ br0,
    float* __restrict__ outp, unsigned short* __restrict__ outbf) {
  int tid = threadIdx.x;
  int row = blockIdx.x * 2 + (tid >> 7);
  int c = tid & 127;
  const float* Wc0  = cw0;                 // [4][128]
  const float* wce0 = cw0 + HD * HD;       // [2][128]
  const float* bc0  = cw0 + HD * HD + 2 * HD;
  float y = 0.f;
#pragma unroll
  for (int k = 0; k < 4; k++) y = fmaf(Sx[row * 4 + k], Wc0[k * HD + c], y);
  y = fmaf(Se[row * 2 + 0], wce0[c], y);
  y = fmaf(Se[row * 2 + 1], wce0[HD + c], y);
  float dg = (float)deg[row];
  y = fmaf(dg, bc0[c], y);
  float dgi = 1.0f / fmaxf(dg, 1.0f);
  y = y * dgi + bno0[c];
  float sc = g0[c] * rsqrtf(v0[c] + BN_EPS);
  float sh = bt0[c] - m0[c] * sc;
  y = y * sc + sh;
  float r = br0[c];
#pragma unroll
  for (int k = 0; k < 4; k++) r = fmaf(x[row * 4 + k], Wr0[k * HD + c], r);
  float o = fmaxf(y + r, 0.f);
  outp[(size_t)row * HD + c] = o;
  outbf[(size_t)row * HD + c] = bf16rne(o);
}

// ---------------- fused layer: dual-edge bf16 gather + MFMA GEMM + epilogue ----------------
// Phase A: gather-sum into LDS, stored split as bf16 hi/lo (St ~= hi+lo, ~f32 precision).
// Phase B: [32x128]x[128x128] via mfma_f32_16x16x32_bf16, 3-term split product
// (hi*hi + lo*hi + hi*lo), f32 accumulate -> ~30x fewer issue slots than v_fma GEMM.

__global__ __launch_bounds__(256, 6) void k_layer(
    const float* __restrict__ h, const unsigned* __restrict__ hbf,
    const int* __restrict__ rowptr, const int* __restrict__ csr,
    const float* __restrict__ cwl, const unsigned short* __restrict__ wmf,
    const float* __restrict__ bno, const float* __restrict__ gam, const float* __restrict__ bet,
    const float* __restrict__ mu, const float* __restrict__ var,
    const float* __restrict__ Se, const int* __restrict__ deg,
    float* __restrict__ outp, unsigned short* __restrict__ outbf) {
  __shared__ unsigned short St_hi[32 * 136];  // 136-pad: 2-way banks (free), 16B-aligned rows
  __shared__ unsigned short St_lo[32 * 136];
  int tid = threadIdx.x;
  int wid = tid >> 6, lane = tid & 63;
  int half = lane >> 5, l5 = lane & 31;
  int rowbase = blockIdx.x * 32;
  const uint2* hb2 = (const uint2*)hbf;   // bf16 row = 32 uint2 = 256 B

  // ---- phase A: each wave aggregates 8 rows; halves walk alternate CSR slots ----
#pragma unroll
  for (int r8 = 0; r8 < 8; r8++) {
    int lr = wid * 8 + r8;
    int i = __builtin_amdgcn_readfirstlane(rowbase + lr);
    float a0 = 0.f, a1 = 0.f, a2 = 0.f, a3 = 0.f;
    if (i < NN) {
      int e0 = rowptr[i], e1 = rowptr[i + 1];
      int e = e0 + half;
      for (; e + 6 < e1; e += 8) {        // 4 loads in flight per half (8 edges/wave-iter)
        int s0 = csr[e], s1 = csr[e + 2], s2 = csr[e + 4], s3 = csr[e + 6];
        uint2 v0 = hb2[(size_t)s0 * 32 + l5];
        uint2 v1 = hb2[(size_t)s1 * 32 + l5];
        uint2 v2 = hb2[(size_t)s2 * 32 + l5];
        uint2 v3 = hb2[(size_t)s3 * 32 + l5];
        a0 += __uint_as_float(v0.x << 16) + __uint_as_float(v1.x << 16)
            + __uint_as_float(v2.x << 16) + __uint_as_float(v3.x << 16);
        a1 += __uint_as_float(v0.x & 0xFFFF0000u) + __uint_as_float(v1.x & 0xFFFF0000u)
            + __uint_as_float(v2.x & 0xFFFF0000u) + __uint_as_float(v3.x & 0xFFFF0000u);
        a2 += __uint_as_float(v0.y << 16) + __uint_as_float(v1.y << 16)
            + __uint_as_float(v2.y << 16) + __uint_as_float(v3.y << 16);
        a3 += __uint_as_float(v0.y & 0xFFFF0000u) + __uint_as_float(v1.y & 0xFFFF0000u)
            + __uint_as_float(v2.y & 0xFFFF0000u) + __uint_as_float(v3.y & 0xFFFF0000u);
      }
      if (e + 2 < e1) {                   // 2-load intermediate (4 edges)
        int s0 = csr[e], s1 = csr[e + 2];
        uint2 v0 = hb2[(size_t)s0 * 32 + l5];
        uint2 v1 = hb2[(size_t)s1 * 32 + l5];
        a0 += __uint_as_float(v0.x << 16) + __uint_as_float(v1.x << 16);
        a1 += __uint_as_float(v0.x & 0xFFFF0000u) + __uint_as_float(v1.x & 0xFFFF0000u);
        a2 += __uint_as_float(v0.y << 16) + __uint_as_float(v1.y << 16);
        a3 += __uint_as_float(v0.y & 0xFFFF0000u) + __uint_as_float(v1.y & 0xFFFF0000u);
        e += 4;
      }
      if (e < e1) {
        uint2 v = hb2[(size_t)csr[e] * 32 + l5];
        a0 += __uint_as_float(v.x << 16);
        a1 += __uint_as_float(v.x & 0xFFFF0000u);
        a2 += __uint_as_float(v.y << 16);
        a3 += __uint_as_float(v.y & 0xFFFF0000u);
      }
    }
    a0 += __shfl_xor(a0, 32);
    a1 += __shfl_xor(a1, 32);
    a2 += __shfl_xor(a2, 32);
    a3 += __shfl_xor(a3, 32);
    if (half == 0) {
      int o = lr * 136 + l5 * 4;
      unsigned short h0, l0, h1, l1, h2, l2, h3, l3;
      bfsplit(a0, h0, l0); bfsplit(a1, h1, l1);
      bfsplit(a2, h2, l2); bfsplit(a3, h3, l3);
      *(ushort4*)&St_hi[o] = make_ushort4(h0, h1, h2, h3);
      *(ushort4*)&St_lo[o] = make_ushort4(l0, l1, l2, l3);
    }
  }
  __syncthreads();

  // ---- phase B: MFMA GEMM. Wave grid 2(M)x2(N): 16 rows x 64 cols per wave ----
  int wm = wid >> 1, wn = wid & 1;
  int nlane = lane & 15, ksub = lane >> 4;
  const unsigned short* wh = wmf;                 // hi table [ks][ksub][col][8]
  const unsigned short* wl = wmf + WMF_L / 2;     // lo table
  f32x4 acc[4];
#pragma unroll
  for (int nt = 0; nt < 4; nt++) acc[nt] = (f32x4){0.f, 0.f, 0.f, 0.f};
  int arow = wm * 16 + nlane;
#pragma unroll
  for (int ks = 0; ks < 4; ks++) {
    bf16x8 ah = *(const bf16x8*)&St_hi[arow * 136 + ks * 32 + ksub * 8];
    bf16x8 al = *(const bf16x8*)&St_lo[arow * 136 + ks * 32 + ksub * 8];
#pragma unroll
    for (int nt = 0; nt < 4; nt++) {
      int col = wn * 64 + nt * 16 + nlane;
      bf16x8 bh = *(const bf16x8*)&wh[(size_t)((ks * 4 + ksub) * 128 + col) * 8];
      bf16x8 bl = *(const bf16x8*)&wl[(size_t)((ks * 4 + ksub) * 128 + col) * 8];
      acc[nt] = __builtin_amdgcn_mfma_f32_16x16x32_bf16(ah, bh, acc[nt], 0, 0, 0);
      acc[nt] = __builtin_amdgcn_mfma_f32_16x16x32_bf16(al, bh, acc[nt], 0, 0, 0);
      acc[nt] = __builtin_amdgcn_mfma_f32_16x16x32_bf16(ah, bl, acc[nt], 0, 0, 0);
    }
  }

  // ---- epilogue: C/D frag lane l reg i -> row=(l>>4)*4+i, col=(l&15)+16*nt ----
  const float* wce = cwl + HD * HD;
  const float* bcp = cwl + HD * HD + 2 * HD;
  int rb = wm * 16 + ksub * 4;
  float dgv[4], dgiv[4];
  float2 sevv[4];
#pragma unroll
  for (int i2 = 0; i2 < 4; i2++) {
    size_t row = (size_t)rowbase + rb + i2;
    float dg = (float)deg[row];
    dgv[i2] = dg;
    dgiv[i2] = 1.0f / fmaxf(dg, 1.0f);
    sevv[i2] = *(const float2*)(Se + row * 2);
  }
#pragma unroll
  for (int nt = 0; nt < 4; nt++) {
    int col = wn * 64 + nt * 16 + nlane;
    float w0 = wce[col], w1 = wce[HD + col], bcv = bcp[col], bnov = bno[col];
    float sc = gam[col] * rsqrtf(var[col] + BN_EPS);
    float sh = bet[col] - mu[col] * sc;
#pragma unroll
    for (int i2 = 0; i2 < 4; i2++) {
      size_t row = (size_t)rowbase + rb + i2;
      float y = (acc[nt][i2] + sevv[i2].x * w0 + sevv[i2].y * w1 + dgv[i2] * bcv) * dgiv[i2] + bnov;
      y = fmaxf(y * sc + sh + h[row * HD + col], 0.f);
      outp[row * HD + col] = y;
      outbf[row * HD + col] = bf16rne(y);
    }
  }
}

// ---------------- pooling (reads bf16 shadow) + head ----------------

__global__ __launch_bounds__(512) void k_pool(
    const unsigned short* __restrict__ hb, const int* __restrict__ batch,
    float* __restrict__ meanp, float* __restrict__ maxp) {
  __shared__ float ssum[512], smax[512];
  int g = blockIdx.x, t = threadIdx.x;
  int d = t & 127, sub = t >> 7;   // 4-way row split
  int lo = 0, hi = NN;
  while (lo < hi) { int mid = (lo + hi) >> 1; if (batch[mid] < g) lo = mid + 1; else hi = mid; }
  int start = lo;
  lo = start; hi = NN;
  while (lo < hi) { int mid = (lo + hi) >> 1; if (batch[mid] < g + 1) lo = mid + 1; else hi = mid; }
  int end = lo;
  float sum = 0.f, mx = -3.4e38f;
  for (int i = start + sub; i < end; i += 4) {
    float val = __uint_as_float((unsigned)hb[(size_t)i * HD + d] << 16);
    sum += val;
    mx = fmaxf(mx, val);
  }
  ssum[t] = sum; smax[t] = mx;
  __syncthreads();
  if (sub == 0) {
    sum = ssum[t] + ssum[t + 128] + ssum[t + 256] + ssum[t + 384];
    mx = fmaxf(fmaxf(smax[t], smax[t + 128]), fmaxf(smax[t + 256], smax[t + 384]));
    int cnt = end - start;
    meanp[g * HD + d] = sum / fmaxf((float)cnt, 1.f);
    maxp[g * HD + d] = (cnt > 0) ? mx : 0.f;
  }
}

__global__ __launch_bounds__(256) void k_head(
    const float* __restrict__ meanp, const float* __restrict__ maxp,
    const float* __restrict__ W1, const float* __restrict__ b1,
    const float* __restrict__ g1, const float* __restrict__ bt1,
    const float* __restrict__ m1, const float* __restrict__ v1,
    const float* __restrict__ W2, const float* __restrict__ b2,
    float* __restrict__ outp) {
  __shared__ float z[256];
  __shared__ float s1[128];
  __shared__ float red[256];
  int g = blockIdx.x, t = threadIdx.x;
  z[t] = (t < 128) ? meanp[g * HD + t] : maxp[g * HD + (t - 128)];
  __syncthreads();
  if (t < 128) {
    float y = b1[t];
    for (int k = 0; k < 256; k++) y = fmaf(z[k], W1[k * HD + t], y);
    float sc = g1[t] * rsqrtf(v1[t] + BN_EPS);
    y = (y - m1[t]) * sc + bt1[t];
    s1[t] = fmaxf(y, 0.f);
  }
  __syncthreads();
  float o = b2[t];
  for (int k = 0; k < 128; k++) o = fmaf(s1[k], W2[k * 256 + t], o);
  red[t] = o * o;
  __syncthreads();
  for (int off = 128; off > 0; off >>= 1) {
    if (t < off) red[t] += red[t + off];
    __syncthreads();
  }
  float scale = 1.0f / fmaxf(sqrtf(red[0]), 1e-12f);
  outp[(size_t)g * 256 + t] = o * scale;
}

// ---------------- launch ----------------

extern "C" void kernel_launch(void* const* d_in, const int* in_sizes, int n_in,
                              void* d_out, int out_size, void* d_ws, size_t ws_size,
                              hipStream_t stream) {
  const float* x         = (const float*)d_in[0];
  const float* edge_attr = (const float*)d_in[1];
  const float* We0  = (const float*)d_in[2];
  const float* be0  = (const float*)d_in[3];
  const float* Wn0  = (const float*)d_in[4];
  const float* bno0 = (const float*)d_in[5];
  const float* g0   = (const float*)d_in[6];
  const float* bt0  = (const float*)d_in[7];
  const float* m0   = (const float*)d_in[8];
  const float* v0   = (const float*)d_in[9];
  const float* Wr0  = (const float*)d_in[10];
  const float* br0  = (const float*)d_in[11];
  const float* We_s = (const float*)d_in[12];
  const float* be_s = (const float*)d_in[13];
  const float* Wn_s = (const float*)d_in[14];
  const float* bno_s= (const float*)d_in[15];
  const float* g_s  = (const float*)d_in[16];
  const float* bt_s = (const float*)d_in[17];
  const float* m_s  = (const float*)d_in[18];
  const float* v_s  = (const float*)d_in[19];
  const float* W1   = (const float*)d_in[20];
  const float* b1   = (const float*)d_in[21];
  const float* g1   = (const float*)d_in[22];
  const float* bt1  = (const float*)d_in[23];
  const float* m1   = (const float*)d_in[24];
  const float* v1   = (const float*)d_in[25];
  const float* W2   = (const float*)d_in[26];
  const float* b2   = (const float*)d_in[27];
  const int* edge_index = (const int*)d_in[28];
  const int* batch      = (const int*)d_in[29];
  float* outp = (float*)d_out;

  char* ws = (char*)d_ws;
  size_t off = 0;
  auto alloc = [&](size_t bytes) -> void* {
    void* p = ws + off;
    off = (off + bytes + 255) & ~(size_t)255;
    return p;
  };
  float* hA    = (float*)alloc((size_t)NPAD * HD * 4);
  float* hB    = (float*)alloc((size_t)NPAD * HD * 4);
  unsigned short* hAbf = (unsigned short*)alloc((size_t)NPAD * HD * 2);
  unsigned short* hBbf = (unsigned short*)alloc((size_t)NPAD * HD * 2);
  float* Sx    = (float*)alloc((size_t)NPAD * 4 * 4);
  float* Se    = (float*)alloc((size_t)NPAD * 2 * 4);
  int*   deg   = (int*)alloc((size_t)NPAD * 4);
  int*   rowptr= (int*)alloc((size_t)(NN + 1) * 4);
  int*   rank  = (int*)alloc((size_t)NE * 4);
  int*   csr   = (int*)alloc((size_t)NE * 4);
  float* eap   = (float*)alloc((size_t)NE * 2 * 4);
  int*   bsum  = (int*)alloc(64 * 4);
  float* cw    = (float*)alloc((size_t)8 * CWS * 4);
  unsigned short* wmf = (unsigned short*)alloc((size_t)7 * WMF_L * 2);
  float* meanp = (float*)alloc((size_t)NG * HD * 4);
  float* maxp  = (float*)alloc((size_t)NG * HD * 4);
  (void)ws_size; (void)n_in; (void)in_sizes; (void)out_size;

  hipMemsetAsync(deg, 0, (size_t)NPAD * 4, stream);
  hipMemsetAsync(Se, 0, (size_t)NPAD * 2 * 4, stream);

  k_deg<<<(NE + 255) / 256, 256, 0, stream>>>(edge_index, deg, rank);
  k_scanA<<<49, 1024, 0, stream>>>(deg, rowptr, bsum);
  k_scanC<<<49, 1024, 0, stream>>>(rowptr, bsum);
  k_scatter<<<(NE + 255) / 256, 256, 0, stream>>>(edge_index, edge_attr, rowptr, rank, csr, eap);
  k_node_pre<<<(NN + 255) / 256, 256, 0, stream>>>(rowptr, csr, eap, x, Sx, Se);
  k_combine<<<8 * 131, 128, 0, stream>>>(We0, be0, Wn0, We_s, be_s, Wn_s, cw, wmf);

  k_layer0<<<NN / 2, 256, 0, stream>>>(x, Sx, Se, deg, cw, bno0, g0, bt0, m0, v0, Wr0, br0,
                                       hA, hAbf);

  float* cur = hA;              float* oth = hB;
  unsigned short* curbf = hAbf; unsigned short* othbf = hBbf;
  for (int l = 1; l <= 7; ++l) {
    int li = l - 1;
    k_layer<<<NPAD / 32, 256, 0, stream>>>(cur, (const unsigned*)curbf, rowptr, csr,
        cw + (size_t)l * CWS, wmf + (size_t)li * WMF_L,
        bno_s + li * HD, g_s + li * HD, bt_s + li * HD, m_s + li * HD, v_s + li * HD,
        Se, deg, oth, othbf);
    float* t = cur; cur = oth; oth = t;
    unsigned short* tb = curbf; curbf = othbf; othbf = tb;
  }

  k_pool<<<NG, 512, 0, stream>>>(curbf, batch, meanp, maxp);
  k_head<<<NG, 256, 0, stream>>>(meanp, maxp, W1, b1, g1, bt1, m1, v1, W2, b2, outp);
}

// Round 7
// 560.346 us; speedup vs baseline: 1.9823x; 1.0547x over previous
//
#include <hip/hip_runtime.h>
#include <hip/hip_bf16.h>

constexpr int NN   = 50000;   // nodes
constexpr int NPAD = 50016;   // padded to multiple of 32 for layer tiles
constexpr int NE   = 600000;  // edges
constexpr int NG   = 512;     // graphs
constexpr int HD   = 128;     // hidden
constexpr float BN_EPS = 1e-5f;
constexpr int CWS  = HD*HD + 2*HD + HD;  // per-layer f32 slot: Wc[128x128], wce[2x128], bc[128]
constexpr int WMF_L = 2*4*4*128*8;       // per-layer split-weight table (ushorts): [hi|lo][ks][ksub][col][8]

typedef __attribute__((ext_vector_type(8))) short bf16x8;
typedef __attribute__((ext_vector_type(4))) float f32x4;

__device__ inline unsigned short bf16rne(float v) {
  unsigned u = __float_as_uint(v);
  return (unsigned short)((u + 0x7FFFu + ((u >> 16) & 1u)) >> 16);
}
// split f32 into hi+lo bf16 (v ~= hi + lo, error ~2^-18 relative)
__device__ inline void bfsplit(float v, unsigned short& h, unsigned short& l) {
  unsigned short hb = bf16rne(v);
  float hf = __uint_as_float((unsigned)hb << 16);
  l = bf16rne(v - hf);
  h = hb;
}
__device__ inline float blo(unsigned u) { return __uint_as_float(u << 16); }
__device__ inline float bhi(unsigned u) { return __uint_as_float(u & 0xFFFF0000u); }

// ---------------- preprocessing ----------------

__global__ __launch_bounds__(256) void k_deg(const int* __restrict__ ei,
                                             int* __restrict__ deg, int* __restrict__ rank) {
  int e = blockIdx.x * 256 + threadIdx.x;
  if (e >= NE) return;
  rank[e] = atomicAdd(&deg[ei[NE + e]], 1);
}

__global__ __launch_bounds__(1024) void k_scanA(const int* __restrict__ deg,
                                                int* __restrict__ rowptr, int* __restrict__ bsum) {
  __shared__ int sm[1024];
  int t = threadIdx.x, b = blockIdx.x;
  int i = b * 1024 + t;
  int v = (i < NN) ? deg[i] : 0;
  sm[t] = v;
  __syncthreads();
  for (int off = 1; off < 1024; off <<= 1) {
    int add = (t >= off) ? sm[t - off] : 0;
    __syncthreads();
    sm[t] += add;
    __syncthreads();
  }
  int incl = sm[t];
  if (i < NN) rowptr[i] = incl - v;   // exclusive within chunk
  if (t == 1023) bsum[b] = incl;
}

// scanB folded in: each block serially prefixes the 49 chunk sums itself
__global__ __launch_bounds__(1024) void k_scanC(int* rowptr, const int* __restrict__ bsum) {
  __shared__ int base;
  int b = blockIdx.x;
  if (threadIdx.x == 0) {
    int acc = 0;
    for (int j = 0; j < b; j++) acc += bsum[j];
    base = acc;
    if (b == 0) rowptr[NN] = NE;
  }
  __syncthreads();
  int i = b * 1024 + threadIdx.x;
  if (i < NN) rowptr[i] += base;
}

__global__ __launch_bounds__(256) void k_scatter(
    const int* __restrict__ ei, const float* __restrict__ ea, const int* __restrict__ rowptr,
    const int* __restrict__ rank, int* __restrict__ csr, float* __restrict__ eap) {
  int e = blockIdx.x * 256 + threadIdx.x;
  if (e >= NE) return;
  int s = ei[e], d = ei[NE + e];
  int pos = rowptr[d] + rank[e];
  csr[pos] = s;
  *(float2*)(eap + 2 * (size_t)pos) = *(const float2*)(ea + 2 * (size_t)e);
}

// per-node sums, 32-lane group per node: lane l loads edges e0+l, e0+l+32, ...
// (was thread-per-node: only 196 blocks / ~3 waves/CU -> latency-bound)
__global__ __launch_bounds__(256) void k_node_pre(
    const int* __restrict__ rowptr, const int* __restrict__ csr, const float* __restrict__ eap,
    const float* __restrict__ x, float* __restrict__ Sx, float* __restrict__ Se) {
  int g32 = threadIdx.x >> 5;
  int i = blockIdx.x * 8 + g32;
  if (i >= NN) return;
  int l = threadIdx.x & 31;
  int e0 = rowptr[i], e1 = rowptr[i + 1];
  float sx0 = 0.f, sx1 = 0.f, sx2 = 0.f, sx3 = 0.f, se0 = 0.f, se1 = 0.f;
  for (int e = e0 + l; e < e1; e += 32) {
    int s = csr[e];
    float4 xv = *(const float4*)(x + 4 * (size_t)s);
    sx0 += xv.x; sx1 += xv.y; sx2 += xv.z; sx3 += xv.w;
    float2 ev = *(const float2*)(eap + 2 * (size_t)e);
    se0 += ev.x; se1 += ev.y;
  }
#pragma unroll
  for (int m = 1; m <= 16; m <<= 1) {
    sx0 += __shfl_xor(sx0, m); sx1 += __shfl_xor(sx1, m);
    sx2 += __shfl_xor(sx2, m); sx3 += __shfl_xor(sx3, m);
    se0 += __shfl_xor(se0, m); se1 += __shfl_xor(se1, m);
  }
  if (l == 0) {
    *(float4*)(Sx + 4 * (size_t)i) = make_float4(sx0, sx1, sx2, sx3);
    *(float2*)(Se + 2 * (size_t)i) = make_float2(se0, se1);
  }
}

// combined weights: Wc = We_h @ Wn (f32), plus split-bf16 MFMA tables for layers 1..7.
// MFMA B-frag layout: lane l holds W[k][col] for col=l&15(+16*nt), k=ks*32+(l>>4)*8+j.
__global__ __launch_bounds__(128) void k_combine(
    const float* __restrict__ We0, const float* __restrict__ be0, const float* __restrict__ Wn0,
    const float* __restrict__ We_s, const float* __restrict__ be_s, const float* __restrict__ Wn_s,
    float* __restrict__ cw, unsigned short* __restrict__ wmf) {
  int l = blockIdx.x / 131;
  int r = blockIdx.x % 131;
  int j = threadIdx.x;
  float* slot = cw + (size_t)l * CWS;
  const float* Wn;
  const float* Arow;
  float* dst;
  if (l == 0) {
    Wn = Wn0;
    if (r < 4)       { Arow = We0 + r * HD; dst = slot + r * HD; }
    else if (r < 6)  { Arow = We0 + r * HD; dst = slot + HD * HD + (r - 4) * HD; }
    else if (r == 6) { Arow = be0;          dst = slot + HD * HD + 2 * HD; }
    else return;
  } else {
    int li = l - 1;
    Wn = Wn_s + (size_t)li * HD * HD;
    const float* We = We_s + (size_t)li * 130 * HD;
    if (r < 128)      { Arow = We + r * HD;  dst = slot + r * HD; }
    else if (r < 130) { Arow = We + r * HD;  dst = slot + HD * HD + (r - 128) * HD; }
    else              { Arow = be_s + li * HD; dst = slot + HD * HD + 2 * HD; }
  }
  float acc = 0.f;
  for (int t = 0; t < HD; t++) acc = fmaf(Arow[t], Wn[t * HD + j], acc);
  dst[j] = acc;
  if (l >= 1 && r < 128) {
    unsigned short hb, lb;
    bfsplit(acc, hb, lb);
    size_t wbase = (size_t)(l - 1) * WMF_L;
    int kb = r >> 5, ks2 = (r >> 3) & 3, jj = r & 7;  // k = r
    size_t o = (size_t)((kb * 4 + ks2) * 128 + j) * 8 + jj;
    wmf[wbase + o] = hb;
    wmf[wbase + WMF_L / 2 + o] = lb;
  }
}

// ---------------- layer 0 (K=4): writes hi/lo bf16 planes ----------------

__global__ __launch_bounds__(256) void k_layer0(
    const float* __restrict__ x, const float* __restrict__ Sx, const float* __restrict__ Se,
    const int* __restrict__ deg, const float* __restrict__ cw0,
    const float* __restrict__ bno0, const float* __restrict__ g0, const float* __restrict__ bt0,
    const float* __restrict__ m0, const float* __restrict__ v0,
    const float* __restrict__ Wr0, const float* __restrict__ br0,
    unsigned short* __restrict__ outHi, unsigned short* __restrict__ outLo) {
  int tid = threadIdx.x;
  int row = blockIdx.x * 2 + (tid >> 7);
  int c = tid & 127;
  const float* Wc0  = cw0;                 // [4][128]
  const float* wce0 = cw0 + HD * HD;       // [2][128]
  const float* bc0  = cw0 + HD * HD + 2 * HD;
  float y = 0.f;
#pragma unroll
  for (int k = 0; k < 4; k++) y = fmaf(Sx[row * 4 + k], Wc0[k * HD + c], y);
  y = fmaf(Se[row * 2 + 0], wce0[c], y);
  y = fmaf(Se[row * 2 + 1], wce0[HD + c], y);
  float dg = (float)deg[row];
  y = fmaf(dg, bc0[c], y);
  float dgi = 1.0f / fmaxf(dg, 1.0f);
  y = y * dgi + bno0[c];
  float sc = g0[c] * rsqrtf(v0[c] + BN_EPS);
  float sh = bt0[c] - m0[c] * sc;
  y = y * sc + sh;
  float r = br0[c];
#pragma unroll
  for (int k = 0; k < 4; k++) r = fmaf(x[row * 4 + k], Wr0[k * HD + c], r);
  float o = fmaxf(y + r, 0.f);
  unsigned short oh, ol;
  bfsplit(o, oh, ol);
  outHi[(size_t)row * HD + c] = oh;
  outLo[(size_t)row * HD + c] = ol;
}

// ---------------- fused layer: row-pair dual-edge gather + MFMA GEMM + epilogue ----------------
// h stored as hi/lo bf16 planes (hi+lo ~= f32). Gather reads hi plane only.
// Phase A: two rows interleaved -> 4 independent loads/round covering 2 rows
// (halves the serial round count per wave). Phase B: split-bf16 MFMA (3-term).

__global__ __launch_bounds__(256, 8) void k_layer(
    const unsigned short* __restrict__ hHi, const unsigned short* __restrict__ hLo,
    const int* __restrict__ rowptr, const int* __restrict__ csr,
    const float* __restrict__ cwl, const unsigned short* __restrict__ wmf,
    const float* __restrict__ bno, const float* __restrict__ gam, const float* __restrict__ bet,
    const float* __restrict__ mu, const float* __restrict__ var,
    const float* __restrict__ Se, const int* __restrict__ deg,
    unsigned short* __restrict__ outHi, unsigned short* __restrict__ outLo) {
  __shared__ unsigned short St_hi[32 * 136];  // 136-pad, 16B-aligned rows
  __shared__ unsigned short St_lo[32 * 136];
  int tid = threadIdx.x;
  int wid = tid >> 6, lane = tid & 63;
  int half = lane >> 5, l5 = lane & 31;
  int rowbase = blockIdx.x * 32;
  const uint2* hb2 = (const uint2*)hHi;   // bf16 row = 32 uint2 = 256 B

  // ---- phase A: row-pair interleaved gather; halves walk alternate CSR slots ----
#pragma unroll
  for (int rp = 0; rp < 4; rp++) {
    int lrA = wid * 8 + rp * 2, lrB = lrA + 1;
    int iA = __builtin_amdgcn_readfirstlane(rowbase + lrA);
    int iB = __builtin_amdgcn_readfirstlane(rowbase + lrB);
    int eA = 0, eA1 = 0, eB = 0, eB1 = 0;
    if (iA < NN) { eA = rowptr[iA] + half; eA1 = rowptr[iA + 1]; }
    if (iB < NN) { eB = rowptr[iB] + half; eB1 = rowptr[iB + 1]; }
    float A0 = 0.f, A1 = 0.f, A2 = 0.f, A3 = 0.f;
    float B0 = 0.f, B1 = 0.f, B2 = 0.f, B3 = 0.f;
    while ((eA + 2 < eA1) && (eB + 2 < eB1)) {   // joint: 4 loads, 2 rows, 8 edges/wave-round
      int sA0 = csr[eA], sA1 = csr[eA + 2], sB0 = csr[eB], sB1 = csr[eB + 2];
      uint2 a0 = hb2[(size_t)sA0 * 32 + l5];
      uint2 a1 = hb2[(size_t)sA1 * 32 + l5];
      uint2 b0 = hb2[(size_t)sB0 * 32 + l5];
      uint2 b1 = hb2[(size_t)sB1 * 32 + l5];
      A0 += blo(a0.x) + blo(a1.x); A1 += bhi(a0.x) + bhi(a1.x);
      A2 += blo(a0.y) + blo(a1.y); A3 += bhi(a0.y) + bhi(a1.y);
      B0 += blo(b0.x) + blo(b1.x); B1 += bhi(b0.x) + bhi(b1.x);
      B2 += blo(b0.y) + blo(b1.y); B3 += bhi(b0.y) + bhi(b1.y);
      eA += 4; eB += 4;
    }
    while (eA + 2 < eA1) {
      int s0 = csr[eA], s1 = csr[eA + 2];
      uint2 a0 = hb2[(size_t)s0 * 32 + l5];
      uint2 a1 = hb2[(size_t)s1 * 32 + l5];
      A0 += blo(a0.x) + blo(a1.x); A1 += bhi(a0.x) + bhi(a1.x);
      A2 += blo(a0.y) + blo(a1.y); A3 += bhi(a0.y) + bhi(a1.y);
      eA += 4;
    }
    if (eA < eA1) {
      uint2 a0 = hb2[(size_t)csr[eA] * 32 + l5];
      A0 += blo(a0.x); A1 += bhi(a0.x); A2 += blo(a0.y); A3 += bhi(a0.y);
    }
    while (eB + 2 < eB1) {
      int s0 = csr[eB], s1 = csr[eB + 2];
      uint2 b0 = hb2[(size_t)s0 * 32 + l5];
      uint2 b1 = hb2[(size_t)s1 * 32 + l5];
      B0 += blo(b0.x) + blo(b1.x); B1 += bhi(b0.x) + bhi(b1.x);
      B2 += blo(b0.y) + blo(b1.y); B3 += bhi(b0.y) + bhi(b1.y);
      eB += 4;
    }
    if (eB < eB1) {
      uint2 b0 = hb2[(size_t)csr[eB] * 32 + l5];
      B0 += blo(b0.x); B1 += bhi(b0.x); B2 += blo(b0.y); B3 += bhi(b0.y);
    }
    A0 += __shfl_xor(A0, 32); A1 += __shfl_xor(A1, 32);
    A2 += __shfl_xor(A2, 32); A3 += __shfl_xor(A3, 32);
    B0 += __shfl_xor(B0, 32); B1 += __shfl_xor(B1, 32);
    B2 += __shfl_xor(B2, 32); B3 += __shfl_xor(B3, 32);
    if (half == 0) {
      unsigned short h0, l0, h1, l1, h2, l2, h3, l3;
      bfsplit(A0, h0, l0); bfsplit(A1, h1, l1); bfsplit(A2, h2, l2); bfsplit(A3, h3, l3);
      *(ushort4*)&St_hi[lrA * 136 + l5 * 4] = make_ushort4(h0, h1, h2, h3);
      *(ushort4*)&St_lo[lrA * 136 + l5 * 4] = make_ushort4(l0, l1, l2, l3);
      bfsplit(B0, h0, l0); bfsplit(B1, h1, l1); bfsplit(B2, h2, l2); bfsplit(B3, h3, l3);
      *(ushort4*)&St_hi[lrB * 136 + l5 * 4] = make_ushort4(h0, h1, h2, h3);
      *(ushort4*)&St_lo[lrB * 136 + l5 * 4] = make_ushort4(l0, l1, l2, l3);
    }
  }
  __syncthreads();

  // ---- phase B: MFMA GEMM. Wave grid 2(M)x2(N): 16 rows x 64 cols per wave ----
  int wm = wid >> 1, wn = wid & 1;
  int nlane = lane & 15, ksub = lane >> 4;
  const unsigned short* wh = wmf;                 // hi table [ks][ksub][col][8]
  const unsigned short* wl = wmf + WMF_L / 2;     // lo table
  f32x4 acc[4];
#pragma unroll
  for (int nt = 0; nt < 4; nt++) acc[nt] = (f32x4){0.f, 0.f, 0.f, 0.f};
  int arow = wm * 16 + nlane;
#pragma unroll
  for (int ks = 0; ks < 4; ks++) {
    bf16x8 ah = *(const bf16x8*)&St_hi[arow * 136 + ks * 32 + ksub * 8];
    bf16x8 al = *(const bf16x8*)&St_lo[arow * 136 + ks * 32 + ksub * 8];
#pragma unroll
    for (int nt = 0; nt < 4; nt++) {
      int col = wn * 64 + nt * 16 + nlane;
      bf16x8 bh = *(const bf16x8*)&wh[(size_t)((ks * 4 + ksub) * 128 + col) * 8];
      bf16x8 bl = *(const bf16x8*)&wl[(size_t)((ks * 4 + ksub) * 128 + col) * 8];
      acc[nt] = __builtin_amdgcn_mfma_f32_16x16x32_bf16(ah, bh, acc[nt], 0, 0, 0);
      acc[nt] = __builtin_amdgcn_mfma_f32_16x16x32_bf16(al, bh, acc[nt], 0, 0, 0);
      acc[nt] = __builtin_amdgcn_mfma_f32_16x16x32_bf16(ah, bl, acc[nt], 0, 0, 0);
    }
  }

  // ---- epilogue: C/D frag lane l reg i -> row=(l>>4)*4+i, col=(l&15)+16*nt ----
  const float* wce = cwl + HD * HD;
  const float* bcp = cwl + HD * HD + 2 * HD;
  int rb = wm * 16 + ksub * 4;
  float dgv[4], dgiv[4];
  float2 sevv[4];
#pragma unroll
  for (int i2 = 0; i2 < 4; i2++) {
    size_t row = (size_t)rowbase + rb + i2;
    float dg = (float)deg[row];
    dgv[i2] = dg;
    dgiv[i2] = 1.0f / fmaxf(dg, 1.0f);
    sevv[i2] = *(const float2*)(Se + row * 2);
  }
#pragma unroll
  for (int nt = 0; nt < 4; nt++) {
    int col = wn * 64 + nt * 16 + nlane;
    float w0 = wce[col], w1 = wce[HD + col], bcv = bcp[col], bnov = bno[col];
    float sc = gam[col] * rsqrtf(var[col] + BN_EPS);
    float sh = bet[col] - mu[col] * sc;
#pragma unroll
    for (int i2 = 0; i2 < 4; i2++) {
      size_t row = (size_t)rowbase + rb + i2;
      size_t idx = row * HD + col;
      float res = blo((unsigned)hHi[idx] << 16 >> 16 << 16) ; // placeholder removed below
      res = __uint_as_float((unsigned)hHi[idx] << 16) + __uint_as_float((unsigned)hLo[idx] << 16);
      float y = (acc[nt][i2] + sevv[i2].x * w0 + sevv[i2].y * w1 + dgv[i2] * bcv) * dgiv[i2] + bnov;
      y = fmaxf(y * sc + sh + res, 0.f);
      unsigned short yh, yl;
      bfsplit(y, yh, yl);
      outHi[idx] = yh;
      outLo[idx] = yl;
    }
  }
}

// ---------------- pooling (reads hi plane) + head ----------------

__global__ __launch_bounds__(512) void k_pool(
    const unsigned short* __restrict__ hb, const int* __restrict__ batch,
    float* __restrict__ meanp, float* __restrict__ maxp) {
  __shared__ float ssum[512], smax[512];
  int g = blockIdx.x, t = threadIdx.x;
  int d = t & 127, sub = t >> 7;   // 4-way row split
  int lo = 0, hi = NN;
  while (lo < hi) { int mid = (lo + hi) >> 1; if (batch[mid] < g) lo = mid + 1; else hi = mid; }
  int start = lo;
  lo = start; hi = NN;
  while (lo < hi) { int mid = (lo + hi) >> 1; if (batch[mid] < g + 1) lo = mid + 1; else hi = mid; }
  int end = lo;
  float sum = 0.f, mx = -3.4e38f;
  for (int i = start + sub; i < end; i += 4) {
    float val = __uint_as_float((unsigned)hb[(size_t)i * HD + d] << 16);
    sum += val;
    mx = fmaxf(mx, val);
  }
  ssum[t] = sum; smax[t] = mx;
  __syncthreads();
  if (sub == 0) {
    sum = ssum[t] + ssum[t + 128] + ssum[t + 256] + ssum[t + 384];
    mx = fmaxf(fmaxf(smax[t], smax[t + 128]), fmaxf(smax[t + 256], smax[t + 384]));
    int cnt = end - start;
    meanp[g * HD + d] = sum / fmaxf((float)cnt, 1.f);
    maxp[g * HD + d] = (cnt > 0) ? mx : 0.f;
  }
}

__global__ __launch_bounds__(256) void k_head(
    const float* __restrict__ meanp, const float* __restrict__ maxp,
    const float* __restrict__ W1, const float* __restrict__ b1,
    const float* __restrict__ g1, const float* __restrict__ bt1,
    const float* __restrict__ m1, const float* __restrict__ v1,
    const float* __restrict__ W2, const float* __restrict__ b2,
    float* __restrict__ outp) {
  __shared__ float z[256];
  __shared__ float s1[128];
  __shared__ float red[256];
  int g = blockIdx.x, t = threadIdx.x;
  z[t] = (t < 128) ? meanp[g * HD + t] : maxp[g * HD + (t - 128)];
  __syncthreads();
  if (t < 128) {
    float y = b1[t];
    for (int k = 0; k < 256; k++) y = fmaf(z[k], W1[k * HD + t], y);
    float sc = g1[t] * rsqrtf(v1[t] + BN_EPS);
    y = (y - m1[t]) * sc + bt1[t];
    s1[t] = fmaxf(y, 0.f);
  }
  __syncthreads();
  float o = b2[t];
  for (int k = 0; k < 128; k++) o = fmaf(s1[k], W2[k * 256 + t], o);
  red[t] = o * o;
  __syncthreads();
  for (int off = 128; off > 0; off >>= 1) {
    if (t < off) red[t] += red[t + off];
    __syncthreads();
  }
  float scale = 1.0f / fmaxf(sqrtf(red[0]), 1e-12f);
  outp[(size_t)g * 256 + t] = o * scale;
}

// ---------------- launch ----------------

extern "C" void kernel_launch(void* const* d_in, const int* in_sizes, int n_in,
                              void* d_out, int out_size, void* d_ws, size_t ws_size,
                              hipStream_t stream) {
  const float* x         = (const float*)d_in[0];
  const float* edge_attr = (const float*)d_in[1];
  const float* We0  = (const float*)d_in[2];
  const float* be0  = (const float*)d_in[3];
  const float* Wn0  = (const float*)d_in[4];
  const float* bno0 = (const float*)d_in[5];
  const float* g0   = (const float*)d_in[6];
  const float* bt0  = (const float*)d_in[7];
  const float* m0   = (const float*)d_in[8];
  const float* v0   = (const float*)d_in[9];
  const float* Wr0  = (const float*)d_in[10];
  const float* br0  = (const float*)d_in[11];
  const float* We_s = (const float*)d_in[12];
  const float* be_s = (const float*)d_in[13];
  const float* Wn_s = (const float*)d_in[14];
  const float* bno_s= (const float*)d_in[15];
  const float* g_s  = (const float*)d_in[16];
  const float* bt_s = (const float*)d_in[17];
  const float* m_s  = (const float*)d_in[18];
  const float* v_s  = (const float*)d_in[19];
  const float* W1   = (const float*)d_in[20];
  const float* b1   = (const float*)d_in[21];
  const float* g1   = (const float*)d_in[22];
  const float* bt1  = (const float*)d_in[23];
  const float* m1   = (const float*)d_in[24];
  const float* v1   = (const float*)d_in[25];
  const float* W2   = (const float*)d_in[26];
  const float* b2   = (const float*)d_in[27];
  const int* edge_index = (const int*)d_in[28];
  const int* batch      = (const int*)d_in[29];
  float* outp = (float*)d_out;

  char* ws = (char*)d_ws;
  size_t off = 0;
  auto alloc = [&](size_t bytes) -> void* {
    void* p = ws + off;
    off = (off + bytes + 255) & ~(size_t)255;
    return p;
  };
  unsigned short* hAHi = (unsigned short*)alloc((size_t)NPAD * HD * 2);
  unsigned short* hALo = (unsigned short*)alloc((size_t)NPAD * HD * 2);
  unsigned short* hBHi = (unsigned short*)alloc((size_t)NPAD * HD * 2);
  unsigned short* hBLo = (unsigned short*)alloc((size_t)NPAD * HD * 2);
  float* Sx    = (float*)alloc((size_t)NPAD * 4 * 4);
  float* Se    = (float*)alloc((size_t)NPAD * 2 * 4);
  int*   deg   = (int*)alloc((size_t)NPAD * 4);
  int*   rowptr= (int*)alloc((size_t)(NN + 1) * 4);
  int*   rank  = (int*)alloc((size_t)NE * 4);
  int*   csr   = (int*)alloc((size_t)NE * 4);
  float* eap   = (float*)alloc((size_t)NE * 2 * 4);
  int*   bsum  = (int*)alloc(64 * 4);
  float* cw    = (float*)alloc((size_t)8 * CWS * 4);
  unsigned short* wmf = (unsigned short*)alloc((size_t)7 * WMF_L * 2);
  float* meanp = (float*)alloc((size_t)NG * HD * 4);
  float* maxp  = (float*)alloc((size_t)NG * HD * 4);
  (void)ws_size; (void)n_in; (void)in_sizes; (void)out_size;

  hipMemsetAsync(deg, 0, (size_t)NPAD * 4, stream);
  hipMemsetAsync(Se, 0, (size_t)NPAD * 2 * 4, stream);   // tail rows read by epilogue

  k_deg<<<(NE + 255) / 256, 256, 0, stream>>>(edge_index, deg, rank);
  k_scanA<<<49, 1024, 0, stream>>>(deg, rowptr, bsum);
  k_scanC<<<49, 1024, 0, stream>>>(rowptr, bsum);
  k_scatter<<<(NE + 255) / 256, 256, 0, stream>>>(edge_index, edge_attr, rowptr, rank, csr, eap);
  k_node_pre<<<(NN + 7) / 8, 256, 0, stream>>>(rowptr, csr, eap, x, Sx, Se);
  k_combine<<<8 * 131, 128, 0, stream>>>(We0, be0, Wn0, We_s, be_s, Wn_s, cw, wmf);

  k_layer0<<<NN / 2, 256, 0, stream>>>(x, Sx, Se, deg, cw, bno0, g0, bt0, m0, v0, Wr0, br0,
                                       hAHi, hALo);

  unsigned short* curHi = hAHi; unsigned short* curLo = hALo;
  unsigned short* othHi = hBHi; unsigned short* othLo = hBLo;
  for (int l = 1; l <= 7; ++l) {
    int li = l - 1;
    k_layer<<<NPAD / 32, 256, 0, stream>>>(curHi, curLo, rowptr, csr,
        cw + (size_t)l * CWS, wmf + (size_t)li * WMF_L,
        bno_s + li * HD, g_s + li * HD, bt_s + li * HD, m_s + li * HD, v_s + li * HD,
        Se, deg, othHi, othLo);
    unsigned short* t;
    t = curHi; curHi = othHi; othHi = t;
    t = curLo; curLo = othLo; othLo = t;
  }

  k_pool<<<NG, 512, 0, stream>>>(curHi, batch, meanp, maxp);
  k_head<<<NG, 256, 0, stream>>>(meanp, maxp, W1, b1, g1, bt1, m1, v1, W2, b2, outp);
}